// Round 5
// baseline (486.213 us; speedup 1.0000x reference)
//
#include <hip/hip_runtime.h>
#include <hip/hip_fp16.h>
#include <math.h>

#define B_      64
#define N_      1024
#define D_      768
#define T_      16
#define SLABS   32          // blocks per batch
#define ROWS_PB 32          // rows per block
#define ROWS_PW 8           // rows per wave (4 waves/block)
#define THR     256

__device__ __forceinline__ float wave_sum(float v) {
    #pragma unroll
    for (int off = 32; off; off >>= 1) v += __shfl_xor(v, off);
    return v;
}

__device__ __forceinline__ uint2 pack4(float4 v) {
    __half2 h0 = __float22half2_rn(make_float2(v.x, v.y));
    __half2 h1 = __float22half2_rn(make_float2(v.z, v.w));
    uint2 u;
    u.x = *(unsigned int*)&h0;
    u.y = *(unsigned int*)&h1;
    return u;
}

__device__ __forceinline__ float4 unpack4(uint2 u) {
    __half2 h0 = *(__half2*)&u.x;
    __half2 h1 = *(__half2*)&u.y;
    float2 a = __half22float2(h0);
    float2 b = __half22float2(h1);
    float4 v; v.x = a.x; v.y = a.y; v.z = b.x; v.w = b.y;
    return v;
}

// per-batch barrier across SLABS blocks (all co-resident; occupancy-checked on host)
__device__ __forceinline__ void batch_barrier(unsigned* bar, int b, unsigned target) {
    __syncthreads();
    if (threadIdx.x == 0) {
        __threadfence();
        __hip_atomic_fetch_add(&bar[b], 1u, __ATOMIC_RELEASE, __HIP_MEMORY_SCOPE_AGENT);
        while (__hip_atomic_load(&bar[b], __ATOMIC_ACQUIRE, __HIP_MEMORY_SCOPE_AGENT) < target)
            __builtin_amdgcn_s_sleep(1);
    }
    __syncthreads();
}

// =================== persistent kernel ===================
__global__ __launch_bounds__(THR, 8)
void k_persist(const float* __restrict__ feat, ushort* __restrict__ f16,
               float* __restrict__ argv2, float* __restrict__ args2,
               int* __restrict__ argi2, float* __restrict__ wsum2,
               float* __restrict__ num2, unsigned* __restrict__ bar,
               float* __restrict__ out) {
    const int blk = blockIdx.x, b = blk >> 5, g = blk & 31;
    const int tid = threadIdx.x, wave = tid >> 6, lane = tid & 63;

    __shared__ __align__(16) float s_red[4 * D_];   // 12 KiB
    __shared__ float s_mask[ROWS_PB], s_sal[ROWS_PB], s_rsal[ROWS_PB], s_msal[ROWS_PB];
    __shared__ float s_wsumW[4];
    __shared__ float s_rsel, s_ws;
    __shared__ int   s_idx;

    const size_t row0   = (size_t)b * N_ + (size_t)g * ROWS_PB;
    const int    APITCH = B_ * SLABS;
    const size_t NPITCH = (size_t)B_ * SLABS * D_;

    // ---- prologue: sal + f16 pack + mask init + slot-0 argmax partials ----
    const int r0 = wave * ROWS_PW;
    #pragma unroll 2
    for (int r = r0; r < r0 + ROWS_PW; ++r) {
        const float4* rp = (const float4*)(feat + (row0 + r) * D_);
        float4 v0 = rp[lane], v1 = rp[lane + 64], v2 = rp[lane + 128];
        uint2* wp = (uint2*)(f16 + (row0 + r) * D_);
        wp[lane]       = pack4(v0);
        wp[lane + 64]  = pack4(v1);
        wp[lane + 128] = pack4(v2);
        float ss = v0.x*v0.x + v0.y*v0.y + v0.z*v0.z + v0.w*v0.w
                 + v1.x*v1.x + v1.y*v1.y + v1.z*v1.z + v1.w*v1.w
                 + v2.x*v2.x + v2.y*v2.y + v2.z*v2.z + v2.w*v2.w;
        ss = wave_sum(ss);
        if (lane == 0) {
            float n = sqrtf(ss);
            s_sal[r]  = n;
            s_rsal[r] = 1.0f / fmaxf(n, 1e-12f);
            s_mask[r] = 1.0f;
            s_msal[r] = n;
        }
    }
    __syncthreads();
    if (wave == 0) {
        float v  = (lane < ROWS_PB) ? s_msal[lane] : -INFINITY;
        float sv = (lane < ROWS_PB) ? s_sal[lane]  : 0.f;
        int   i  = (lane < ROWS_PB) ? (g * ROWS_PB + lane) : 0x7fffffff;
        #pragma unroll
        for (int off = 32; off; off >>= 1) {
            float ov = __shfl_xor(v, off);
            float osv = __shfl_xor(sv, off);
            int   oi = __shfl_xor(i, off);
            if (ov > v || (ov == v && oi < i)) { v = ov; sv = osv; i = oi; }
        }
        if (lane == 0) {
            argv2[b*SLABS + g] = v;     // parity 0
            args2[b*SLABS + g] = sv;
            argi2[b*SLABS + g] = i;
        }
    }
    batch_barrier(bar, b, 32u);

    // ---- slot loop ----
    for (int t = 0; t < T_; ++t) {
        const int pi = t & 1;          // this slot's selection / this slot's partial writes
        const int po = (t + 1) & 1;    // prev slot's partials ((t-1)&1) / next slot's argmax

        // step1: cross-slab selection reduce (+ prev wsum)
        if (wave == 0) {
            float v  = (lane < SLABS) ? argv2[pi*APITCH + b*SLABS + lane] : -INFINITY;
            float sv = (lane < SLABS) ? args2[pi*APITCH + b*SLABS + lane] : 0.f;
            int   i  = (lane < SLABS) ? argi2[pi*APITCH + b*SLABS + lane] : 0x7fffffff;
            float w  = (t > 0 && lane < SLABS) ? wsum2[po*APITCH + b*SLABS + lane] : 0.f;
            #pragma unroll
            for (int off = 32; off; off >>= 1) {
                float ov = __shfl_xor(v, off);
                float osv = __shfl_xor(sv, off);
                int   oi = __shfl_xor(i, off);
                w += __shfl_xor(w, off);
                if (ov > v || (ov == v && oi < i)) { v = ov; sv = osv; i = oi; }
            }
            if (lane == 0) { s_idx = i; s_rsel = 1.0f / fmaxf(sv, 1e-12f); s_ws = w; }
        }
        __syncthreads();

        // step2: write out[t-1] (4 blocks per batch)
        if (t > 0 && g < 4 && tid < 192) {
            const int c = g * 192 + tid;
            float s = 0.f;
            #pragma unroll 8
            for (int gg = 0; gg < SLABS; ++gg)
                s += num2[po*NPITCH + ((size_t)b*SLABS + gg)*D_ + c];
            out[((size_t)b * T_ + (t-1)) * D_ + c] = s / (s_ws + 1e-8f);
        }

        // step3: normalized selected-row fragments (f32 source)
        const float rsel = s_rsel;
        const float4* selp = (const float4*)(feat + ((size_t)b * N_ + s_idx) * D_);
        float4 sel0 = selp[lane], sel1 = selp[lane + 64], sel2 = selp[lane + 128];
        sel0.x *= rsel; sel0.y *= rsel; sel0.z *= rsel; sel0.w *= rsel;
        sel1.x *= rsel; sel1.y *= rsel; sel1.z *= rsel; sel1.w *= rsel;
        sel2.x *= rsel; sel2.y *= rsel; sel2.z *= rsel; sel2.w *= rsel;

        // step4: fused pass over own 32 rows (f16 reads, LDS mask)
        float4 acc0 = {0.f,0.f,0.f,0.f};
        float4 acc1 = {0.f,0.f,0.f,0.f};
        float4 acc2 = {0.f,0.f,0.f,0.f};
        float  wsl  = 0.f;
        #pragma unroll 2
        for (int r = r0; r < r0 + ROWS_PW; ++r) {
            const uint2* rp = (const uint2*)(f16 + (row0 + r) * D_);
            uint2 u0 = rp[lane], u1 = rp[lane + 64], u2 = rp[lane + 128];
            float4 v0 = unpack4(u0), v1 = unpack4(u1), v2 = unpack4(u2);

            float dot = 0.f;
            dot = fmaf(v0.x, sel0.x, dot); dot = fmaf(v0.y, sel0.y, dot);
            dot = fmaf(v0.z, sel0.z, dot); dot = fmaf(v0.w, sel0.w, dot);
            dot = fmaf(v1.x, sel1.x, dot); dot = fmaf(v1.y, sel1.y, dot);
            dot = fmaf(v1.z, sel1.z, dot); dot = fmaf(v1.w, sel1.w, dot);
            dot = fmaf(v2.x, sel2.x, dot); dot = fmaf(v2.y, sel2.y, dot);
            dot = fmaf(v2.z, sel2.z, dot); dot = fmaf(v2.w, sel2.w, dot);
            dot = wave_sum(dot);

            float sim = dot * s_rsal[r];
            float m   = s_mask[r];
            float wr  = (sim > 0.5f) ? (sim * m) : 0.f;
            float nm  = m * (1.0f - fminf(fmaxf(sim, 0.f), 1.f));
            if (lane == 0) { s_mask[r] = nm; s_msal[r] = s_sal[r] * nm; }

            wsl += wr;
            acc0.x = fmaf(wr, v0.x, acc0.x); acc0.y = fmaf(wr, v0.y, acc0.y);
            acc0.z = fmaf(wr, v0.z, acc0.z); acc0.w = fmaf(wr, v0.w, acc0.w);
            acc1.x = fmaf(wr, v1.x, acc1.x); acc1.y = fmaf(wr, v1.y, acc1.y);
            acc1.z = fmaf(wr, v1.z, acc1.z); acc1.w = fmaf(wr, v1.w, acc1.w);
            acc2.x = fmaf(wr, v2.x, acc2.x); acc2.y = fmaf(wr, v2.y, acc2.y);
            acc2.z = fmaf(wr, v2.z, acc2.z); acc2.w = fmaf(wr, v2.w, acc2.w);
        }

        // step5: partial writes
        {
            float4* red = (float4*)(s_red + wave * D_);
            red[lane]       = acc0;
            red[lane + 64]  = acc1;
            red[lane + 128] = acc2;
            if (lane == 0) s_wsumW[wave] = wsl;
        }
        __syncthreads();
        for (int c = tid; c < D_; c += THR) {
            float s = s_red[c] + s_red[D_ + c] + s_red[2*D_ + c] + s_red[3*D_ + c];
            num2[pi*NPITCH + ((size_t)b*SLABS + g)*D_ + c] = s;
        }
        if (tid == 0)
            wsum2[pi*APITCH + b*SLABS + g] = s_wsumW[0] + s_wsumW[1] + s_wsumW[2] + s_wsumW[3];
        if (wave == 0) {
            float v  = (lane < ROWS_PB) ? s_msal[lane] : -INFINITY;
            float sv = (lane < ROWS_PB) ? s_sal[lane]  : 0.f;
            int   i  = (lane < ROWS_PB) ? (g * ROWS_PB + lane) : 0x7fffffff;
            #pragma unroll
            for (int off = 32; off; off >>= 1) {
                float ov = __shfl_xor(v, off);
                float osv = __shfl_xor(sv, off);
                int   oi = __shfl_xor(i, off);
                if (ov > v || (ov == v && oi < i)) { v = ov; sv = osv; i = oi; }
            }
            if (lane == 0) {
                argv2[po*APITCH + b*SLABS + g] = v;
                args2[po*APITCH + b*SLABS + g] = sv;
                argi2[po*APITCH + b*SLABS + g] = i;
            }
        }
        batch_barrier(bar, b, 32u * (unsigned)(t + 2));
    }

    // ---- epilogue: out[T-1] ----
    if (g < 4) {
        if (wave == 0) {
            float w = (lane < SLABS) ? wsum2[((T_-1)&1)*APITCH + b*SLABS + lane] : 0.f;
            #pragma unroll
            for (int off = 32; off; off >>= 1) w += __shfl_xor(w, off);
            if (lane == 0) s_ws = w;
        }
        __syncthreads();
        if (tid < 192) {
            const int c = g * 192 + tid;
            float s = 0.f;
            #pragma unroll 8
            for (int gg = 0; gg < SLABS; ++gg)
                s += num2[((T_-1)&1)*NPITCH + ((size_t)b*SLABS + gg)*D_ + c];
            out[((size_t)b * T_ + (T_-1)) * D_ + c] = s / (s_ws + 1e-8f);
        }
    }
}

// =================== fallback: r4 multi-kernel fp16 path ===================
__global__ __launch_bounds__(THR)
void k_sal16(const float* __restrict__ feat, ushort* __restrict__ f16,
             float* __restrict__ sal, float* __restrict__ rsal,
             float* __restrict__ mask, float* __restrict__ argv,
             float* __restrict__ args, int* __restrict__ argi) {
    const int blk = blockIdx.x, b = blk >> 5, g = blk & 31;
    const int tid = threadIdx.x, wave = tid >> 6, lane = tid & 63;
    __shared__ float s_sal[ROWS_PB];
    const size_t row0 = (size_t)b * N_ + (size_t)g * ROWS_PB;
    const int r0 = wave * ROWS_PW;
    #pragma unroll 2
    for (int r = r0; r < r0 + ROWS_PW; ++r) {
        const float4* rp = (const float4*)(feat + (row0 + r) * D_);
        float4 v0 = rp[lane], v1 = rp[lane + 64], v2 = rp[lane + 128];
        uint2* wp = (uint2*)(f16 + (row0 + r) * D_);
        wp[lane] = pack4(v0); wp[lane+64] = pack4(v1); wp[lane+128] = pack4(v2);
        float ss = v0.x*v0.x + v0.y*v0.y + v0.z*v0.z + v0.w*v0.w
                 + v1.x*v1.x + v1.y*v1.y + v1.z*v1.z + v1.w*v1.w
                 + v2.x*v2.x + v2.y*v2.y + v2.z*v2.z + v2.w*v2.w;
        ss = wave_sum(ss);
        if (lane == 0) s_sal[r] = sqrtf(ss);
    }
    __syncthreads();
    const int rg = b * N_ + g * ROWS_PB;
    if (tid < ROWS_PB) {
        float n = s_sal[tid];
        sal[rg + tid] = n; rsal[rg + tid] = 1.0f / fmaxf(n, 1e-12f); mask[rg + tid] = 1.0f;
    }
    if (wave == 0) {
        float v  = (lane < ROWS_PB) ? s_sal[lane] : -INFINITY;
        float sv = v;
        int   i  = (lane < ROWS_PB) ? (g * ROWS_PB + lane) : 0x7fffffff;
        #pragma unroll
        for (int off = 32; off; off >>= 1) {
            float ov = __shfl_xor(v, off);
            float osv = __shfl_xor(sv, off);
            int   oi = __shfl_xor(i, off);
            if (ov > v || (ov == v && oi < i)) { v = ov; sv = osv; i = oi; }
        }
        if (lane == 0) { argv[b*SLABS+g] = v; args[b*SLABS+g] = sv; argi[b*SLABS+g] = i; }
    }
}

__global__ __launch_bounds__(THR)
void k_fused16(const ushort* __restrict__ f16, const float* __restrict__ sel,
               const float* __restrict__ sal, const float* __restrict__ rsal,
               float* __restrict__ mask, float* __restrict__ num,
               float* __restrict__ wsum, float* __restrict__ argv,
               float* __restrict__ args, int* __restrict__ argi) {
    const int blk = blockIdx.x, b = blk >> 5, g = blk & 31;
    const int tid = threadIdx.x, wave = tid >> 6, lane = tid & 63;
    __shared__ __align__(16) float s_red[4 * D_];
    __shared__ float s_wsum[4];
    __shared__ float s_msal[ROWS_PB];
    __shared__ float s_salL[ROWS_PB];
    const size_t row0 = (size_t)b * N_ + (size_t)g * ROWS_PB;
    const float4* selp = (const float4*)(sel + (size_t)b * D_);
    float4 sel0 = selp[lane], sel1 = selp[lane + 64], sel2 = selp[lane + 128];
    float4 acc0 = {0.f,0.f,0.f,0.f}, acc1 = {0.f,0.f,0.f,0.f}, acc2 = {0.f,0.f,0.f,0.f};
    float wsl = 0.f;
    const int rbase = b * N_ + g * ROWS_PB;
    const int r0 = wave * ROWS_PW;
    #pragma unroll 2
    for (int r = r0; r < r0 + ROWS_PW; ++r) {
        const uint2* rp = (const uint2*)(f16 + (row0 + r) * D_);
        uint2 u0 = rp[lane], u1 = rp[lane + 64], u2 = rp[lane + 128];
        float4 v0 = unpack4(u0), v1 = unpack4(u1), v2 = unpack4(u2);
        float dot = 0.f;
        dot = fmaf(v0.x, sel0.x, dot); dot = fmaf(v0.y, sel0.y, dot);
        dot = fmaf(v0.z, sel0.z, dot); dot = fmaf(v0.w, sel0.w, dot);
        dot = fmaf(v1.x, sel1.x, dot); dot = fmaf(v1.y, sel1.y, dot);
        dot = fmaf(v1.z, sel1.z, dot); dot = fmaf(v1.w, sel1.w, dot);
        dot = fmaf(v2.x, sel2.x, dot); dot = fmaf(v2.y, sel2.y, dot);
        dot = fmaf(v2.z, sel2.z, dot); dot = fmaf(v2.w, sel2.w, dot);
        dot = wave_sum(dot);
        float rs = rsal[rbase + r], sv = sal[rbase + r], m = mask[rbase + r];
        float sim = dot * rs;
        float wr = (sim > 0.5f) ? (sim * m) : 0.f;
        float nm = m * (1.0f - fminf(fmaxf(sim, 0.f), 1.f));
        if (lane == 0) { mask[rbase + r] = nm; s_msal[r] = sv * nm; s_salL[r] = sv; }
        wsl += wr;
        acc0.x = fmaf(wr, v0.x, acc0.x); acc0.y = fmaf(wr, v0.y, acc0.y);
        acc0.z = fmaf(wr, v0.z, acc0.z); acc0.w = fmaf(wr, v0.w, acc0.w);
        acc1.x = fmaf(wr, v1.x, acc1.x); acc1.y = fmaf(wr, v1.y, acc1.y);
        acc1.z = fmaf(wr, v1.z, acc1.z); acc1.w = fmaf(wr, v1.w, acc1.w);
        acc2.x = fmaf(wr, v2.x, acc2.x); acc2.y = fmaf(wr, v2.y, acc2.y);
        acc2.z = fmaf(wr, v2.z, acc2.z); acc2.w = fmaf(wr, v2.w, acc2.w);
    }
    {
        float4* red = (float4*)(s_red + wave * D_);
        red[lane] = acc0; red[lane + 64] = acc1; red[lane + 128] = acc2;
        if (lane == 0) s_wsum[wave] = wsl;
    }
    __syncthreads();
    for (int c = tid; c < D_; c += THR) {
        float s = s_red[c] + s_red[D_ + c] + s_red[2*D_ + c] + s_red[3*D_ + c];
        num[((size_t)b * SLABS + g) * D_ + c] = s;
    }
    if (tid == 0) wsum[b*SLABS+g] = s_wsum[0] + s_wsum[1] + s_wsum[2] + s_wsum[3];
    if (wave == 0) {
        float v  = (lane < ROWS_PB) ? s_msal[lane] : -INFINITY;
        float sv = (lane < ROWS_PB) ? s_salL[lane] : 0.f;
        int   i  = (lane < ROWS_PB) ? (g * ROWS_PB + lane) : 0x7fffffff;
        #pragma unroll
        for (int off = 32; off; off >>= 1) {
            float ov = __shfl_xor(v, off);
            float osv = __shfl_xor(sv, off);
            int   oi = __shfl_xor(i, off);
            if (ov > v || (ov == v && oi < i)) { v = ov; sv = osv; i = oi; }
        }
        if (lane == 0) { argv[b*SLABS+g] = v; args[b*SLABS+g] = sv; argi[b*SLABS+g] = i; }
    }
}

__global__ __launch_bounds__(192)
void k_out(const float* __restrict__ feat, const float* __restrict__ num,
           const float* __restrict__ wsumA, const float* __restrict__ argv,
           const float* __restrict__ args, const int* __restrict__ argi,
           float* __restrict__ sel, float* __restrict__ out, int t) {
    const int b = blockIdx.x >> 2, q = blockIdx.x & 3;
    const int tid = threadIdx.x, lane = tid & 63;
    __shared__ float s_rsel;
    __shared__ int   s_idx;
    __shared__ float s_ws;
    if (tid < 64) {
        float v  = (lane < SLABS) ? argv[b*SLABS + lane] : -INFINITY;
        float sv = (lane < SLABS) ? args[b*SLABS + lane] : 0.f;
        int   i  = (lane < SLABS) ? argi[b*SLABS + lane] : 0x7fffffff;
        float w  = (lane < SLABS) ? wsumA[b*SLABS + lane] : 0.f;
        #pragma unroll
        for (int off = 32; off; off >>= 1) {
            float ov = __shfl_xor(v, off);
            float osv = __shfl_xor(sv, off);
            int   oi = __shfl_xor(i, off);
            w += __shfl_xor(w, off);
            if (ov > v || (ov == v && oi < i)) { v = ov; sv = osv; i = oi; }
        }
        if (lane == 0) { s_idx = i; s_rsel = 1.0f / fmaxf(sv, 1e-12f); s_ws = w; }
    }
    __syncthreads();
    const int c = q * 192 + tid;
    if (t >= 0) {
        float s = 0.f;
        #pragma unroll 8
        for (int g = 0; g < SLABS; ++g)
            s += num[((size_t)b * SLABS + g) * D_ + c];
        out[((size_t)b * T_ + t) * D_ + c] = s / (s_ws + 1e-8f);
    }
    sel[(size_t)b * D_ + c] = feat[((size_t)b * N_ + s_idx) * D_ + c] * s_rsel;
}

// =================== last-resort mono kernel ===================
__global__ __launch_bounds__(1024, 1)
void greedy_mono(const float* __restrict__ feat, float* __restrict__ out) {
    const int b = blockIdx.x, tid = threadIdx.x, wave = tid >> 6, lane = tid & 63;
    __shared__ float s_mask[N_], s_sal[N_], s_rsal[N_];
    __shared__ __align__(16) float s_sel[D_];
    __shared__ __align__(16) float s_red[16 * D_];
    __shared__ float s_wsum[16], s_argv[16];
    __shared__ int s_argi[16], s_idx;
    const float* fb = feat + (size_t)b * N_ * D_;
    {
        const int r0 = wave * 64;
        for (int r = r0; r < r0 + 64; ++r) {
            const float4* rp = (const float4*)(fb + (size_t)r * D_);
            float4 v0 = rp[lane], v1 = rp[lane+64], v2 = rp[lane+128];
            float ss = v0.x*v0.x+v0.y*v0.y+v0.z*v0.z+v0.w*v0.w
                     + v1.x*v1.x+v1.y*v1.y+v1.z*v1.z+v1.w*v1.w
                     + v2.x*v2.x+v2.y*v2.y+v2.z*v2.z+v2.w*v2.w;
            ss = wave_sum(ss);
            if (lane == 0) { float n = sqrtf(ss); s_sal[r]=n; s_rsal[r]=1.f/fmaxf(n,1e-12f); s_mask[r]=1.f; }
        }
    }
    __syncthreads();
    for (int t = 0; t < T_; ++t) {
        {
            float bv = s_sal[tid] * s_mask[tid]; int bi = tid;
            #pragma unroll
            for (int off = 32; off; off >>= 1) {
                float ov = __shfl_xor(bv, off); int oi = __shfl_xor(bi, off);
                if (ov > bv || (ov == bv && oi < bi)) { bv = ov; bi = oi; }
            }
            if (lane == 0) { s_argv[wave] = bv; s_argi[wave] = bi; }
        }
        __syncthreads();
        if (tid == 0) {
            float best = s_argv[0]; int besti = s_argi[0];
            #pragma unroll
            for (int w = 1; w < 16; ++w) {
                float v = s_argv[w]; int i = s_argi[w];
                if (v > best || (v == best && i < besti)) { best = v; besti = i; }
            }
            s_idx = besti;
        }
        __syncthreads();
        const int idx = s_idx;
        if (tid < D_) s_sel[tid] = fb[(size_t)idx*D_+tid] * (1.f/fmaxf(s_sal[idx],1e-12f));
        __syncthreads();
        const float4* selp = (const float4*)s_sel;
        float4 sel0 = selp[lane], sel1 = selp[lane+64], sel2 = selp[lane+128];
        float4 a0={0,0,0,0}, a1={0,0,0,0}, a2={0,0,0,0}; float wsl=0.f;
        const int r0 = wave * 64;
        for (int r = r0; r < r0 + 64; ++r) {
            const float4* rp = (const float4*)(fb + (size_t)r * D_);
            float4 v0 = rp[lane], v1 = rp[lane+64], v2 = rp[lane+128];
            float dot = 0.f;
            dot=fmaf(v0.x,sel0.x,dot); dot=fmaf(v0.y,sel0.y,dot); dot=fmaf(v0.z,sel0.z,dot); dot=fmaf(v0.w,sel0.w,dot);
            dot=fmaf(v1.x,sel1.x,dot); dot=fmaf(v1.y,sel1.y,dot); dot=fmaf(v1.z,sel1.z,dot); dot=fmaf(v1.w,sel1.w,dot);
            dot=fmaf(v2.x,sel2.x,dot); dot=fmaf(v2.y,sel2.y,dot); dot=fmaf(v2.z,sel2.z,dot); dot=fmaf(v2.w,sel2.w,dot);
            dot = wave_sum(dot);
            float sim = dot * s_rsal[r], m = s_mask[r];
            float wr = (sim > 0.5f) ? (sim * m) : 0.f;
            if (lane == 0) s_mask[r] = m * (1.f - fminf(fmaxf(sim,0.f),1.f));
            wsl += wr;
            a0.x=fmaf(wr,v0.x,a0.x); a0.y=fmaf(wr,v0.y,a0.y); a0.z=fmaf(wr,v0.z,a0.z); a0.w=fmaf(wr,v0.w,a0.w);
            a1.x=fmaf(wr,v1.x,a1.x); a1.y=fmaf(wr,v1.y,a1.y); a1.z=fmaf(wr,v1.z,a1.z); a1.w=fmaf(wr,v1.w,a1.w);
            a2.x=fmaf(wr,v2.x,a2.x); a2.y=fmaf(wr,v2.y,a2.y); a2.z=fmaf(wr,v2.z,a2.z); a2.w=fmaf(wr,v2.w,a2.w);
        }
        {
            float4* red = (float4*)(s_red + wave * D_);
            red[lane]=a0; red[lane+64]=a1; red[lane+128]=a2;
            if (lane == 0) s_wsum[wave] = wsl;
        }
        __syncthreads();
        if (tid < D_) {
            float s = 0.f, den = 0.f;
            #pragma unroll
            for (int w = 0; w < 16; ++w) { s += s_red[w*D_+tid]; den += s_wsum[w]; }
            out[((size_t)b*T_+t)*D_+tid] = s / (den + 1e-8f);
        }
        __syncthreads();
    }
}

extern "C" void kernel_launch(void* const* d_in, const int* in_sizes, int n_in,
                              void* d_out, int out_size, void* d_ws, size_t ws_size,
                              hipStream_t stream) {
    const float* feat = (const float*)d_in[0];
    float* out = (float*)d_out;
    (void)in_sizes; (void)n_in; (void)out_size;

    const size_t n_sal = (size_t)B_ * N_;
    const size_t n_arg = (size_t)B_ * SLABS;
    const size_t n_sel = (size_t)B_ * D_;
    const size_t n_num = (size_t)B_ * SLABS * D_;
    const size_t n_f16 = (size_t)B_ * N_ * D_;       // ushort

    const size_t f16_bytes = (n_f16 * sizeof(ushort) + 255) & ~(size_t)255;

    // ---- persistent path layout ----
    const size_t need_persist = f16_bytes
        + 2 * n_num * sizeof(float)                  // num2
        + 2 * n_arg * (3 * sizeof(float) + sizeof(int))  // argv2,args2,wsum2,argi2
        + B_ * sizeof(unsigned) + 1024;

    // ---- r4 multi-kernel path layout ----
    const size_t need_mk = f16_bytes
        + (3*n_sal + 4*n_arg + n_sel + n_num) * sizeof(float) + 1024;

    // occupancy preflight for co-residency (deadlock safety)
    int dev = 0; (void)hipGetDevice(&dev);
    int cu = 0;
    (void)hipDeviceGetAttribute(&cu, hipDeviceAttributeMultiprocessorCount, dev);
    int nb = 0;
    hipError_t oe = hipOccupancyMaxActiveBlocksPerMultiprocessor(
        &nb, reinterpret_cast<const void*>(k_persist), THR, 0);
    const bool co_resident = (oe == hipSuccess) && ((long)nb * cu >= B_ * SLABS);

    if (co_resident && ws_size >= need_persist) {
        char* base = (char*)d_ws;
        ushort* f16 = (ushort*)base;
        char* q = base + f16_bytes;
        float* num2  = (float*)q;  q += 2 * n_num * sizeof(float);
        float* argv2 = (float*)q;  q += 2 * n_arg * sizeof(float);
        float* args2 = (float*)q;  q += 2 * n_arg * sizeof(float);
        float* wsum2 = (float*)q;  q += 2 * n_arg * sizeof(float);
        int*   argi2 = (int*)q;    q += 2 * n_arg * sizeof(int);
        unsigned* bar = (unsigned*)q;

        hipMemsetAsync(bar, 0, B_ * sizeof(unsigned), stream);
        k_persist<<<B_*SLABS, THR, 0, stream>>>(feat, f16, argv2, args2, argi2,
                                                wsum2, num2, bar, out);
        return;
    }

    if (ws_size >= need_mk) {
        char* base = (char*)d_ws;
        ushort* f16 = (ushort*)base;
        float* p = (float*)(base + f16_bytes);
        float* sal  = p;            p += n_sal;
        float* rsal = p;            p += n_sal;
        float* mask = p;            p += n_sal;
        float* argv = p;            p += n_arg;
        float* args = p;            p += n_arg;
        int*   argi = (int*)p;      p += n_arg;
        float* wsum = p;            p += n_arg;
        float* sel  = p;            p += n_sel;
        float* num  = p;            p += n_num;

        k_sal16<<<B_*SLABS, THR, 0, stream>>>(feat, f16, sal, rsal, mask, argv, args, argi);
        k_out<<<B_*4, 192, 0, stream>>>(feat, num, wsum, argv, args, argi, sel, out, -1);
        for (int t = 0; t < T_; ++t) {
            k_fused16<<<B_*SLABS, THR, 0, stream>>>(f16, sel, sal, rsal, mask,
                                                    num, wsum, argv, args, argi);
            k_out<<<B_*4, 192, 0, stream>>>(feat, num, wsum, argv, args, argi, sel, out, t);
        }
        return;
    }

    greedy_mono<<<B_, 1024, 0, stream>>>(feat, out);
}

// Round 6
// 483.063 us; speedup vs baseline: 1.0065x; 1.0065x over previous
//
#include <hip/hip_runtime.h>
#include <hip/hip_fp16.h>
#include <math.h>

#define B_      64
#define N_      1024
#define D_      768
#define T_      16
#define SLABS   32          // blocks per batch in pass kernels
#define ROWS_PB 32          // rows per block
#define ROWS_PW 8           // rows per wave (4 waves/block)
#define THR     256
#define CPL     24          // cols per lane in half-wave scheme (768/32)

__device__ __forceinline__ float wave_sum(float v) {
    #pragma unroll
    for (int off = 32; off; off >>= 1) v += __shfl_xor(v, off);
    return v;
}

__device__ __forceinline__ float half_sum(float v) {   // within 32-lane half
    #pragma unroll
    for (int off = 16; off; off >>= 1) v += __shfl_xor(v, off);
    return v;
}

__device__ __forceinline__ unsigned pack2(float a, float b) {
    __half2 h = __float22half2_rn(make_float2(a, b));
    return *(unsigned*)&h;
}

__device__ __forceinline__ void unpack8(uint4 u, float* f) {
    __half2 h; float2 q;
    h = *(__half2*)&u.x; q = __half22float2(h); f[0] = q.x; f[1] = q.y;
    h = *(__half2*)&u.y; q = __half22float2(h); f[2] = q.x; f[3] = q.y;
    h = *(__half2*)&u.z; q = __half22float2(h); f[4] = q.x; f[5] = q.y;
    h = *(__half2*)&u.w; q = __half22float2(h); f[6] = q.x; f[7] = q.y;
}

// ---------------- pass 0: saliency + f16 pack (16B loads/stores) ----------------
__global__ __launch_bounds__(THR)
void k_sal16v(const float* __restrict__ feat, ushort* __restrict__ f16,
              float* __restrict__ sal, float* __restrict__ rsal,
              float* __restrict__ mask, float* __restrict__ argv,
              float* __restrict__ args, int* __restrict__ argi) {
    const int blk = blockIdx.x, b = blk >> 5, g = blk & 31;
    const int tid = threadIdx.x, wave = tid >> 6, lane = tid & 63;
    const int h = lane >> 5, s = lane & 31;
    __shared__ float s_sal[ROWS_PB];

    const size_t row0 = (size_t)b * N_ + (size_t)g * ROWS_PB;
    const int r0 = wave * ROWS_PW;

    #pragma unroll
    for (int rp = 0; rp < ROWS_PW / 2; ++rp) {
        const int r = r0 + rp * 2 + h;
        const float4* fp4 = (const float4*)(feat + (row0 + r) * D_ + s * CPL);
        float4 a0 = fp4[0], a1 = fp4[1], a2 = fp4[2], a3 = fp4[3], a4 = fp4[4], a5 = fp4[5];

        uint4 w0, w1, w2;
        w0.x = pack2(a0.x, a0.y); w0.y = pack2(a0.z, a0.w);
        w0.z = pack2(a1.x, a1.y); w0.w = pack2(a1.z, a1.w);
        w1.x = pack2(a2.x, a2.y); w1.y = pack2(a2.z, a2.w);
        w1.z = pack2(a3.x, a3.y); w1.w = pack2(a3.z, a3.w);
        w2.x = pack2(a4.x, a4.y); w2.y = pack2(a4.z, a4.w);
        w2.z = pack2(a5.x, a5.y); w2.w = pack2(a5.z, a5.w);
        uint4* wp = (uint4*)(f16 + (row0 + r) * D_ + s * CPL);
        wp[0] = w0; wp[1] = w1; wp[2] = w2;

        float ss = a0.x*a0.x + a0.y*a0.y + a0.z*a0.z + a0.w*a0.w
                 + a1.x*a1.x + a1.y*a1.y + a1.z*a1.z + a1.w*a1.w
                 + a2.x*a2.x + a2.y*a2.y + a2.z*a2.z + a2.w*a2.w
                 + a3.x*a3.x + a3.y*a3.y + a3.z*a3.z + a3.w*a3.w
                 + a4.x*a4.x + a4.y*a4.y + a4.z*a4.z + a4.w*a4.w
                 + a5.x*a5.x + a5.y*a5.y + a5.z*a5.z + a5.w*a5.w;
        ss = half_sum(ss);
        if (s == 0) s_sal[r] = sqrtf(ss);
    }
    __syncthreads();

    const int rg = b * N_ + g * ROWS_PB;
    if (tid < ROWS_PB) {
        float n = s_sal[tid];
        sal[rg + tid]  = n;
        rsal[rg + tid] = 1.0f / fmaxf(n, 1e-12f);
        mask[rg + tid] = 1.0f;
    }
    if (wave == 0) {
        float v  = (lane < ROWS_PB) ? s_sal[lane] : -INFINITY;
        float sv = v;
        int   i  = (lane < ROWS_PB) ? (g * ROWS_PB + lane) : 0x7fffffff;
        #pragma unroll
        for (int off = 32; off; off >>= 1) {
            float ov = __shfl_xor(v, off);
            float osv = __shfl_xor(sv, off);
            int   oi = __shfl_xor(i, off);
            if (ov > v || (ov == v && oi < i)) { v = ov; sv = osv; i = oi; }
        }
        if (lane == 0) { argv[b*SLABS+g] = v; args[b*SLABS+g] = sv; argi[b*SLABS+g] = i; }
    }
}

// ---------------- per-slot main pass: 16B f16 loads, 2 rows per wave-iter ----------------
__global__ __launch_bounds__(THR)
void k_fusedv(const ushort* __restrict__ f16, const float* __restrict__ sel,
              const float* __restrict__ sal, const float* __restrict__ rsal,
              float* __restrict__ mask, float* __restrict__ num,
              float* __restrict__ wsum, float* __restrict__ argv,
              float* __restrict__ args, int* __restrict__ argi) {
    const int blk = blockIdx.x, b = blk >> 5, g = blk & 31;
    const int tid = threadIdx.x, wave = tid >> 6, lane = tid & 63;
    const int h = lane >> 5, s = lane & 31;

    __shared__ __align__(16) float s_red[4 * D_];   // 12 KiB
    __shared__ float s_wsumW[4];
    __shared__ float s_msal[ROWS_PB];
    __shared__ float s_salL[ROWS_PB];

    const size_t row0 = (size_t)b * N_ + (size_t)g * ROWS_PB;
    const int rbase = b * N_ + g * ROWS_PB;
    const int r0 = wave * ROWS_PW;

    // preload this lane's 24 sel values (f32)
    float se[CPL];
    {
        const float4* sp = (const float4*)(sel + (size_t)b * D_ + s * CPL);
        #pragma unroll
        for (int q = 0; q < 6; ++q) {
            float4 v = sp[q];
            se[q*4+0] = v.x; se[q*4+1] = v.y; se[q*4+2] = v.z; se[q*4+3] = v.w;
        }
    }

    float acc[CPL];
    #pragma unroll
    for (int i = 0; i < CPL; ++i) acc[i] = 0.f;
    float wsl = 0.f;

    #pragma unroll
    for (int rp = 0; rp < ROWS_PW / 2; ++rp) {
        const int r = r0 + rp * 2 + h;
        const uint4* dp = (const uint4*)(f16 + (row0 + r) * D_ + s * CPL);
        uint4 u0 = dp[0], u1 = dp[1], u2 = dp[2];
        float f[CPL];
        unpack8(u0, f); unpack8(u1, f + 8); unpack8(u2, f + 16);

        float dot = 0.f;
        #pragma unroll
        for (int i = 0; i < CPL; ++i) dot = fmaf(f[i], se[i], dot);
        dot = half_sum(dot);

        float rs  = rsal[rbase + r];
        float sv  = sal[rbase + r];
        float m   = mask[rbase + r];
        float sim = dot * rs;
        float wr  = (sim > 0.5f) ? (sim * m) : 0.f;
        float nm  = m * (1.0f - fminf(fmaxf(sim, 0.f), 1.f));

        if (s == 0) {
            mask[rbase + r] = nm;
            s_msal[r] = sv * nm;
            s_salL[r] = sv;
        }

        wsl += wr;
        #pragma unroll
        for (int i = 0; i < CPL; ++i) acc[i] = fmaf(wr, f[i], acc[i]);
    }

    // combine halves (rows r and r+1 accumulated into same column ownership)
    wsl += __shfl_xor(wsl, 32);
    #pragma unroll
    for (int i = 0; i < CPL; ++i) acc[i] += __shfl_xor(acc[i], 32);

    if (h == 0) {
        float4* rw = (float4*)(s_red + wave * D_ + s * CPL);
        #pragma unroll
        for (int q = 0; q < 6; ++q) {
            float4 v;
            v.x = acc[q*4+0]; v.y = acc[q*4+1]; v.z = acc[q*4+2]; v.w = acc[q*4+3];
            rw[q] = v;
        }
    }
    if (lane == 0) s_wsumW[wave] = wsl;
    __syncthreads();

    #pragma unroll
    for (int it = 0; it < 3; ++it) {
        const int c = it * THR + tid;
        float sm = s_red[c] + s_red[D_ + c] + s_red[2*D_ + c] + s_red[3*D_ + c];
        num[((size_t)b * SLABS + g) * D_ + c] = sm;
    }
    if (tid == 0)
        wsum[b*SLABS+g] = s_wsumW[0] + s_wsumW[1] + s_wsumW[2] + s_wsumW[3];

    if (wave == 0) {
        float v  = (lane < ROWS_PB) ? s_msal[lane] : -INFINITY;
        float sv = (lane < ROWS_PB) ? s_salL[lane] : 0.f;
        int   i  = (lane < ROWS_PB) ? (g * ROWS_PB + lane) : 0x7fffffff;
        #pragma unroll
        for (int off = 32; off; off >>= 1) {
            float ov = __shfl_xor(v, off);
            float osv = __shfl_xor(sv, off);
            int   oi = __shfl_xor(i, off);
            if (ov > v || (ov == v && oi < i)) { v = ov; sv = osv; i = oi; }
        }
        if (lane == 0) { argv[b*SLABS+g] = v; args[b*SLABS+g] = sv; argi[b*SLABS+g] = i; }
    }
}

// ---------------- per-slot reduce: write out[t], compute next sel (exact f32) ----------------
__global__ __launch_bounds__(192)
void k_out(const float* __restrict__ feat, const float* __restrict__ num,
           const float* __restrict__ wsumA, const float* __restrict__ argv,
           const float* __restrict__ args, const int* __restrict__ argi,
           float* __restrict__ sel, float* __restrict__ out, int t) {
    const int b = blockIdx.x >> 2, q = blockIdx.x & 3;
    const int tid = threadIdx.x, lane = tid & 63;

    __shared__ float s_rsel;
    __shared__ int   s_idx;
    __shared__ float s_ws;

    if (tid < 64) {
        float v  = (lane < SLABS) ? argv[b*SLABS + lane] : -INFINITY;
        float sv = (lane < SLABS) ? args[b*SLABS + lane] : 0.f;
        int   i  = (lane < SLABS) ? argi[b*SLABS + lane] : 0x7fffffff;
        float w  = (lane < SLABS) ? wsumA[b*SLABS + lane] : 0.f;
        #pragma unroll
        for (int off = 32; off; off >>= 1) {
            float ov = __shfl_xor(v, off);
            float osv = __shfl_xor(sv, off);
            int   oi = __shfl_xor(i, off);
            w += __shfl_xor(w, off);
            if (ov > v || (ov == v && oi < i)) { v = ov; sv = osv; i = oi; }
        }
        if (lane == 0) {
            s_idx  = i;
            s_rsel = 1.0f / fmaxf(sv, 1e-12f);
            s_ws   = w;
        }
    }
    __syncthreads();

    const int c = q * 192 + tid;
    if (t >= 0) {
        float sm = 0.f;
        #pragma unroll 8
        for (int g = 0; g < SLABS; ++g)
            sm += num[((size_t)b * SLABS + g) * D_ + c];
        out[((size_t)b * T_ + t) * D_ + c] = sm / (s_ws + 1e-8f);
    }
    sel[(size_t)b * D_ + c] = feat[((size_t)b * N_ + s_idx) * D_ + c] * s_rsel;
}

// ---------------- last-resort mono kernel ----------------
__global__ __launch_bounds__(1024, 1)
void greedy_mono(const float* __restrict__ feat, float* __restrict__ out) {
    const int b = blockIdx.x, tid = threadIdx.x, wave = tid >> 6, lane = tid & 63;
    __shared__ float s_mask[N_], s_sal[N_], s_rsal[N_];
    __shared__ __align__(16) float s_sel[D_];
    __shared__ __align__(16) float s_red[16 * D_];
    __shared__ float s_wsum[16], s_argv[16];
    __shared__ int s_argi[16], s_idx;
    const float* fb = feat + (size_t)b * N_ * D_;
    {
        const int r0 = wave * 64;
        for (int r = r0; r < r0 + 64; ++r) {
            const float4* rp = (const float4*)(fb + (size_t)r * D_);
            float4 v0 = rp[lane], v1 = rp[lane+64], v2 = rp[lane+128];
            float ss = v0.x*v0.x+v0.y*v0.y+v0.z*v0.z+v0.w*v0.w
                     + v1.x*v1.x+v1.y*v1.y+v1.z*v1.z+v1.w*v1.w
                     + v2.x*v2.x+v2.y*v2.y+v2.z*v2.z+v2.w*v2.w;
            ss = wave_sum(ss);
            if (lane == 0) { float n = sqrtf(ss); s_sal[r]=n; s_rsal[r]=1.f/fmaxf(n,1e-12f); s_mask[r]=1.f; }
        }
    }
    __syncthreads();
    for (int t = 0; t < T_; ++t) {
        {
            float bv = s_sal[tid] * s_mask[tid]; int bi = tid;
            #pragma unroll
            for (int off = 32; off; off >>= 1) {
                float ov = __shfl_xor(bv, off); int oi = __shfl_xor(bi, off);
                if (ov > bv || (ov == bv && oi < bi)) { bv = ov; bi = oi; }
            }
            if (lane == 0) { s_argv[wave] = bv; s_argi[wave] = bi; }
        }
        __syncthreads();
        if (tid == 0) {
            float best = s_argv[0]; int besti = s_argi[0];
            #pragma unroll
            for (int w = 1; w < 16; ++w) {
                float v = s_argv[w]; int i = s_argi[w];
                if (v > best || (v == best && i < besti)) { best = v; besti = i; }
            }
            s_idx = besti;
        }
        __syncthreads();
        const int idx = s_idx;
        if (tid < D_) s_sel[tid] = fb[(size_t)idx*D_+tid] * (1.f/fmaxf(s_sal[idx],1e-12f));
        __syncthreads();
        const float4* selp = (const float4*)s_sel;
        float4 sel0 = selp[lane], sel1 = selp[lane+64], sel2 = selp[lane+128];
        float4 a0={0,0,0,0}, a1={0,0,0,0}, a2={0,0,0,0}; float wsl=0.f;
        const int r0 = wave * 64;
        for (int r = r0; r < r0 + 64; ++r) {
            const float4* rp = (const float4*)(fb + (size_t)r * D_);
            float4 v0 = rp[lane], v1 = rp[lane+64], v2 = rp[lane+128];
            float dot = 0.f;
            dot=fmaf(v0.x,sel0.x,dot); dot=fmaf(v0.y,sel0.y,dot); dot=fmaf(v0.z,sel0.z,dot); dot=fmaf(v0.w,sel0.w,dot);
            dot=fmaf(v1.x,sel1.x,dot); dot=fmaf(v1.y,sel1.y,dot); dot=fmaf(v1.z,sel1.z,dot); dot=fmaf(v1.w,sel1.w,dot);
            dot=fmaf(v2.x,sel2.x,dot); dot=fmaf(v2.y,sel2.y,dot); dot=fmaf(v2.z,sel2.z,dot); dot=fmaf(v2.w,sel2.w,dot);
            dot = wave_sum(dot);
            float sim = dot * s_rsal[r], m = s_mask[r];
            float wr = (sim > 0.5f) ? (sim * m) : 0.f;
            if (lane == 0) s_mask[r] = m * (1.f - fminf(fmaxf(sim,0.f),1.f));
            wsl += wr;
            a0.x=fmaf(wr,v0.x,a0.x); a0.y=fmaf(wr,v0.y,a0.y); a0.z=fmaf(wr,v0.z,a0.z); a0.w=fmaf(wr,v0.w,a0.w);
            a1.x=fmaf(wr,v1.x,a1.x); a1.y=fmaf(wr,v1.y,a1.y); a1.z=fmaf(wr,v1.z,a1.z); a1.w=fmaf(wr,v1.w,a1.w);
            a2.x=fmaf(wr,v2.x,a2.x); a2.y=fmaf(wr,v2.y,a2.y); a2.z=fmaf(wr,v2.z,a2.z); a2.w=fmaf(wr,v2.w,a2.w);
        }
        {
            float4* red = (float4*)(s_red + wave * D_);
            red[lane]=a0; red[lane+64]=a1; red[lane+128]=a2;
            if (lane == 0) s_wsum[wave] = wsl;
        }
        __syncthreads();
        if (tid < D_) {
            float sm = 0.f, den = 0.f;
            #pragma unroll
            for (int w = 0; w < 16; ++w) { sm += s_red[w*D_+tid]; den += s_wsum[w]; }
            out[((size_t)b*T_+t)*D_+tid] = sm / (den + 1e-8f);
        }
        __syncthreads();
    }
}

extern "C" void kernel_launch(void* const* d_in, const int* in_sizes, int n_in,
                              void* d_out, int out_size, void* d_ws, size_t ws_size,
                              hipStream_t stream) {
    const float* feat = (const float*)d_in[0];
    float* out = (float*)d_out;
    (void)in_sizes; (void)n_in; (void)out_size;

    const size_t n_sal = (size_t)B_ * N_;
    const size_t n_arg = (size_t)B_ * SLABS;
    const size_t n_sel = (size_t)B_ * D_;
    const size_t n_num = (size_t)B_ * SLABS * D_;
    const size_t n_f16 = (size_t)B_ * N_ * D_;     // ushort elements

    const size_t f16_bytes = (n_f16 * sizeof(ushort) + 255) & ~(size_t)255;
    const size_t need_mk = f16_bytes
        + (3*n_sal + 4*n_arg + n_sel + n_num) * sizeof(float) + 1024;

    if (ws_size >= need_mk) {
        char* base = (char*)d_ws;
        ushort* f16 = (ushort*)base;
        float* p = (float*)(base + f16_bytes);
        float* sal  = p;            p += n_sal;
        float* rsal = p;            p += n_sal;
        float* mask = p;            p += n_sal;
        float* argv = p;            p += n_arg;
        float* args = p;            p += n_arg;
        int*   argi = (int*)p;      p += n_arg;
        float* wsum = p;            p += n_arg;
        float* sel  = p;            p += n_sel;
        float* num  = p;            p += n_num;

        k_sal16v<<<B_*SLABS, THR, 0, stream>>>(feat, f16, sal, rsal, mask, argv, args, argi);
        k_out<<<B_*4, 192, 0, stream>>>(feat, num, wsum, argv, args, argi, sel, out, -1);
        for (int t = 0; t < T_; ++t) {
            k_fusedv<<<B_*SLABS, THR, 0, stream>>>(f16, sel, sal, rsal, mask,
                                                   num, wsum, argv, args, argi);
            k_out<<<B_*4, 192, 0, stream>>>(feat, num, wsum, argv, args, argi, sel, out, t);
        }
        return;
    }

    greedy_mono<<<B_, 1024, 0, stream>>>(feat, out);
}

// Round 7
// 431.173 us; speedup vs baseline: 1.1277x; 1.1203x over previous
//
#include <hip/hip_runtime.h>
#include <hip/hip_fp16.h>
#include <math.h>

#define B_      64
#define N_      1024
#define D_      768
#define T_      16
#define SLABS   32
#define ROWS_PB 32
#define ROWS_PW 8
#define THR     256
#define CPL     24

typedef _Float16 half8 __attribute__((ext_vector_type(8)));
typedef float    f32x4 __attribute__((ext_vector_type(4)));

__device__ __forceinline__ float wave_sum(float v) {
    #pragma unroll
    for (int off = 32; off; off >>= 1) v += __shfl_xor(v, off);
    return v;
}
__device__ __forceinline__ float half_sum(float v) {
    #pragma unroll
    for (int off = 16; off; off >>= 1) v += __shfl_xor(v, off);
    return v;
}
__device__ __forceinline__ unsigned pack2(float a, float b) {
    __half2 h = __float22half2_rn(make_float2(a, b));
    return *(unsigned*)&h;
}
__device__ __forceinline__ void unpack8(uint4 u, float* f) {
    __half2 h; float2 q;
    h = *(__half2*)&u.x; q = __half22float2(h); f[0] = q.x; f[1] = q.y;
    h = *(__half2*)&u.y; q = __half22float2(h); f[2] = q.x; f[3] = q.y;
    h = *(__half2*)&u.z; q = __half22float2(h); f[4] = q.x; f[5] = q.y;
    h = *(__half2*)&u.w; q = __half22float2(h); f[6] = q.x; f[7] = q.y;
}

// ---------------- pass 0: saliency + f16 pack ----------------
__global__ __launch_bounds__(THR)
void k_sal16v(const float* __restrict__ feat, ushort* __restrict__ f16,
              float* __restrict__ sal, float* __restrict__ rsal,
              float* __restrict__ mask, float* __restrict__ argv,
              float* __restrict__ args, int* __restrict__ argi) {
    const int blk = blockIdx.x, b = blk >> 5, g = blk & 31;
    const int tid = threadIdx.x, wave = tid >> 6, lane = tid & 63;
    const int h = lane >> 5, s = lane & 31;
    __shared__ float s_sal[ROWS_PB];

    const size_t row0 = (size_t)b * N_ + (size_t)g * ROWS_PB;
    const int r0 = wave * ROWS_PW;

    #pragma unroll
    for (int rp = 0; rp < ROWS_PW / 2; ++rp) {
        const int r = r0 + rp * 2 + h;
        const float4* fp4 = (const float4*)(feat + (row0 + r) * D_ + s * CPL);
        float4 a0 = fp4[0], a1 = fp4[1], a2 = fp4[2], a3 = fp4[3], a4 = fp4[4], a5 = fp4[5];
        uint4 w0, w1, w2;
        w0.x = pack2(a0.x, a0.y); w0.y = pack2(a0.z, a0.w);
        w0.z = pack2(a1.x, a1.y); w0.w = pack2(a1.z, a1.w);
        w1.x = pack2(a2.x, a2.y); w1.y = pack2(a2.z, a2.w);
        w1.z = pack2(a3.x, a3.y); w1.w = pack2(a3.z, a3.w);
        w2.x = pack2(a4.x, a4.y); w2.y = pack2(a4.z, a4.w);
        w2.z = pack2(a5.x, a5.y); w2.w = pack2(a5.z, a5.w);
        uint4* wp = (uint4*)(f16 + (row0 + r) * D_ + s * CPL);
        wp[0] = w0; wp[1] = w1; wp[2] = w2;

        float ss = a0.x*a0.x + a0.y*a0.y + a0.z*a0.z + a0.w*a0.w
                 + a1.x*a1.x + a1.y*a1.y + a1.z*a1.z + a1.w*a1.w
                 + a2.x*a2.x + a2.y*a2.y + a2.z*a2.z + a2.w*a2.w
                 + a3.x*a3.x + a3.y*a3.y + a3.z*a3.z + a3.w*a3.w
                 + a4.x*a4.x + a4.y*a4.y + a4.z*a4.z + a4.w*a4.w
                 + a5.x*a5.x + a5.y*a5.y + a5.z*a5.z + a5.w*a5.w;
        ss = half_sum(ss);
        if (s == 0) s_sal[r] = sqrtf(ss);
    }
    __syncthreads();

    const int rg = b * N_ + g * ROWS_PB;
    if (tid < ROWS_PB) {
        float n = s_sal[tid];
        sal[rg + tid]  = n;
        rsal[rg + tid] = 1.0f / fmaxf(n, 1e-12f);
        mask[rg + tid] = 1.0f;
    }
    if (wave == 0) {
        float v  = (lane < ROWS_PB) ? s_sal[lane] : -INFINITY;
        float sv = v;
        int   i  = (lane < ROWS_PB) ? (g * ROWS_PB + lane) : 0x7fffffff;
        #pragma unroll
        for (int off = 32; off; off >>= 1) {
            float ov = __shfl_xor(v, off);
            float osv = __shfl_xor(sv, off);
            int   oi = __shfl_xor(i, off);
            if (ov > v || (ov == v && oi < i)) { v = ov; sv = osv; i = oi; }
        }
        if (lane == 0) { argv[b*SLABS+g] = v; args[b*SLABS+g] = sv; argi[b*SLABS+g] = i; }
    }
}

// ---------------- Gram GEMM: G[b] = F16[b] * F16[b]^T, f32 out ----------------
// 128x128 tile per block, 4 waves (2x2), each wave 64x64 (4x4 frags 16x16),
// BK=64, reg-staged LDS with XOR swizzle: chunk (r,kc) stored at halves
// r*64 + ((kc ^ (r&7))*8). Writes linear (dest-index driven), reads swizzled.
__global__ __launch_bounds__(THR)
void k_gram(const ushort* __restrict__ f16, float* __restrict__ G) {
    const int bid = blockIdx.x;
    const int batch = bid >> 6, tile = bid & 63;
    const int trow = tile >> 3, tcol = tile & 7;
    const int tid = threadIdx.x, wave = tid >> 6, lane = tid & 63;
    const int wr = wave >> 1, wc = wave & 1;

    __shared__ __align__(16) ushort lA[128 * 64];
    __shared__ __align__(16) ushort lB[128 * 64];

    const ushort* Fb = f16 + (size_t)batch * N_ * D_;
    const int row0 = trow * 128, col0 = tcol * 128;

    f32x4 acc[4][4];
    #pragma unroll
    for (int i = 0; i < 4; ++i)
        #pragma unroll
        for (int j = 0; j < 4; ++j)
            acc[i][j] = (f32x4){0.f, 0.f, 0.f, 0.f};

    for (int k0 = 0; k0 < D_; k0 += 64) {
        // stage A and B (dest-linear writes, source picks swizzled chunk)
        #pragma unroll
        for (int i = 0; i < 4; ++i) {
            const int d  = i * THR + tid;        // 16B dest chunk index 0..1023
            const int r  = d >> 3;
            const int kc = (d & 7) ^ (r & 7);    // global chunk for this slot
            const uint4 va = *(const uint4*)(Fb + (size_t)(row0 + r) * D_ + k0 + kc * 8);
            *(uint4*)(lA + (size_t)d * 8) = va;
            const uint4 vb = *(const uint4*)(Fb + (size_t)(col0 + r) * D_ + k0 + kc * 8);
            *(uint4*)(lB + (size_t)d * 8) = vb;
        }
        __syncthreads();

        #pragma unroll
        for (int ks = 0; ks < 2; ++ks) {
            half8 af[4], bf[4];
            #pragma unroll
            for (int fr = 0; fr < 4; ++fr) {
                const int rl = wr * 64 + fr * 16 + (lane & 15);
                const int kch = ks * 4 + (lane >> 4);
                af[fr] = *(const half8*)(lA + rl * 64 + ((kch ^ (rl & 7)) * 8));
            }
            #pragma unroll
            for (int fc = 0; fc < 4; ++fc) {
                const int cl = wc * 64 + fc * 16 + (lane & 15);
                const int kch = ks * 4 + (lane >> 4);
                bf[fc] = *(const half8*)(lB + cl * 64 + ((kch ^ (cl & 7)) * 8));
            }
            #pragma unroll
            for (int fr = 0; fr < 4; ++fr)
                #pragma unroll
                for (int fc = 0; fc < 4; ++fc)
                    acc[fr][fc] = __builtin_amdgcn_mfma_f32_16x16x32_f16(
                        af[fr], bf[fc], acc[fr][fc], 0, 0, 0);
        }
        __syncthreads();
    }

    // epilogue: C/D mapping col=lane&15, row=(lane>>4)*4+q  [m89]
    float* Gb = G + ((size_t)batch << 20);
    #pragma unroll
    for (int fr = 0; fr < 4; ++fr) {
        #pragma unroll
        for (int fc = 0; fc < 4; ++fc) {
            const int rbase = row0 + wr * 64 + fr * 16 + (lane >> 4) * 4;
            const int c     = col0 + wc * 64 + fc * 16 + (lane & 15);
            #pragma unroll
            for (int q = 0; q < 4; ++q)
                Gb[(size_t)(rbase + q) * N_ + c] = acc[fr][fc][q];
        }
    }
}

// ---------------- slot loop: selection + mask + weights, all from G ----------------
__global__ __launch_bounds__(THR)
void k_slots(const float* __restrict__ G, const float* __restrict__ sal,
             const float* __restrict__ rsal, float* __restrict__ wbuf,
             float* __restrict__ wsum) {
    const int b = blockIdx.x, tid = threadIdx.x, wave = tid >> 6, lane = tid & 63;

    __shared__ float s_sal[N_], s_rsal[N_], s_mask[N_], s_msal[N_];
    __shared__ float s_av[4], s_wv[4];
    __shared__ int   s_ai[4];
    __shared__ int   s_idx;
    __shared__ float s_rsidx;

    #pragma unroll
    for (int k = 0; k < 4; ++k) {
        const int n = tid + k * THR;
        float sv = sal[b * N_ + n];
        s_sal[n]  = sv;
        s_rsal[n] = rsal[b * N_ + n];
        s_mask[n] = 1.0f;
        s_msal[n] = sv;
    }
    __syncthreads();

    const float* Gb = G + ((size_t)b << 20);

    for (int t = 0; t < T_; ++t) {
        // argmax over msal (ties -> lowest index)
        {
            float v = -INFINITY; int i = 0x7fffffff;
            #pragma unroll
            for (int k = 0; k < 4; ++k) {
                const int n = tid + k * THR;
                float x = s_msal[n];
                if (x > v || (x == v && n < i)) { v = x; i = n; }
            }
            #pragma unroll
            for (int off = 32; off; off >>= 1) {
                float ov = __shfl_xor(v, off);
                int   oi = __shfl_xor(i, off);
                if (ov > v || (ov == v && oi < i)) { v = ov; i = oi; }
            }
            if (lane == 0) { s_av[wave] = v; s_ai[wave] = i; }
        }
        __syncthreads();
        if (tid == 0) {
            float v = s_av[0]; int i = s_ai[0];
            #pragma unroll
            for (int w = 1; w < 4; ++w) {
                float ov = s_av[w]; int oi = s_ai[w];
                if (ov > v || (ov == v && oi < i)) { v = ov; i = oi; }
            }
            s_idx = i;
            s_rsidx = s_rsal[i];
        }
        __syncthreads();

        const int idx = s_idx;
        const float rsi = s_rsidx;

        float wloc = 0.f;
        #pragma unroll
        for (int k = 0; k < 4; ++k) {
            const int n = tid + k * THR;
            float gv  = Gb[(size_t)idx * N_ + n];
            float sim = gv * s_rsal[n] * rsi;
            float m   = s_mask[n];
            float w   = (sim > 0.5f) ? (sim * m) : 0.f;
            float nm  = m * (1.0f - fminf(fmaxf(sim, 0.f), 1.f));
            s_mask[n] = nm;
            s_msal[n] = s_sal[n] * nm;
            wbuf[((size_t)(b * T_ + t)) * N_ + n] = w;
            wloc += w;
        }
        wloc = wave_sum(wloc);
        if (lane == 0) s_wv[wave] = wloc;
        __syncthreads();
        if (tid == 0)
            wsum[b * T_ + t] = s_wv[0] + s_wv[1] + s_wv[2] + s_wv[3];
        __syncthreads();
    }
}

// ---------------- W*F partials: 4 row-groups per batch ----------------
__global__ __launch_bounds__(THR)
void k_wf(const ushort* __restrict__ f16, const float* __restrict__ wbuf,
          float* __restrict__ part) {
    const int bid = blockIdx.x, b = bid >> 2, rg = bid & 3;
    const int tid = threadIdx.x;

    __shared__ float s_w[T_ * 256];    // 16 KiB: w[t][r] for this row group

    for (int idx = tid; idx < T_ * 256; idx += THR) {
        const int t = idx >> 8, r = idx & 255;
        s_w[idx] = wbuf[((size_t)(b * T_ + t)) * N_ + rg * 256 + r];
    }
    __syncthreads();

    float acc[T_][3];
    #pragma unroll
    for (int t = 0; t < T_; ++t) { acc[t][0] = 0.f; acc[t][1] = 0.f; acc[t][2] = 0.f; }

    const _Float16* Fb = (const _Float16*)(f16 + (size_t)b * N_ * D_);
    for (int r = 0; r < 256; ++r) {
        const _Float16* row = Fb + (size_t)(rg * 256 + r) * D_;
        const float f0 = (float)row[tid];
        const float f1 = (float)row[tid + 256];
        const float f2 = (float)row[tid + 512];
        const float* wr = s_w + r;
        #pragma unroll
        for (int t = 0; t < T_; ++t) {
            const float w = wr[t << 8];
            acc[t][0] = fmaf(w, f0, acc[t][0]);
            acc[t][1] = fmaf(w, f1, acc[t][1]);
            acc[t][2] = fmaf(w, f2, acc[t][2]);
        }
    }

    float* pb = part + (((size_t)(b * 4 + rg)) * T_) * D_;
    #pragma unroll
    for (int t = 0; t < T_; ++t) {
        pb[(size_t)t * D_ + tid]       = acc[t][0];
        pb[(size_t)t * D_ + tid + 256] = acc[t][1];
        pb[(size_t)t * D_ + tid + 512] = acc[t][2];
    }
}

// ---------------- final reduce + normalize ----------------
__global__ __launch_bounds__(THR)
void k_red(const float* __restrict__ part, const float* __restrict__ wsum,
           float* __restrict__ out) {
    const int bid = blockIdx.x, b = bid >> 4, t = bid & 15;
    const int tid = threadIdx.x;
    const float den = wsum[b * T_ + t] + 1e-8f;
    #pragma unroll
    for (int j = 0; j < 3; ++j) {
        const int c = tid + j * 256;
        float s = 0.f;
        #pragma unroll
        for (int rg = 0; rg < 4; ++rg)
            s += part[(((size_t)(b * 4 + rg)) * T_ + t) * D_ + c];
        out[((size_t)(b * T_ + t)) * D_ + c] = s / den;
    }
}

// ================= fallback: r6 streaming path =================
__global__ __launch_bounds__(THR)
void k_fusedv(const ushort* __restrict__ f16, const float* __restrict__ sel,
              const float* __restrict__ sal, const float* __restrict__ rsal,
              float* __restrict__ mask, float* __restrict__ num,
              float* __restrict__ wsum, float* __restrict__ argv,
              float* __restrict__ args, int* __restrict__ argi) {
    const int blk = blockIdx.x, b = blk >> 5, g = blk & 31;
    const int tid = threadIdx.x, wave = tid >> 6, lane = tid & 63;
    const int h = lane >> 5, s = lane & 31;
    __shared__ __align__(16) float s_red[4 * D_];
    __shared__ float s_wsumW[4];
    __shared__ float s_msal[ROWS_PB];
    __shared__ float s_salL[ROWS_PB];
    const size_t row0 = (size_t)b * N_ + (size_t)g * ROWS_PB;
    const int rbase = b * N_ + g * ROWS_PB;
    const int r0 = wave * ROWS_PW;
    float se[CPL];
    {
        const float4* sp = (const float4*)(sel + (size_t)b * D_ + s * CPL);
        #pragma unroll
        for (int q = 0; q < 6; ++q) {
            float4 v = sp[q];
            se[q*4+0] = v.x; se[q*4+1] = v.y; se[q*4+2] = v.z; se[q*4+3] = v.w;
        }
    }
    float acc[CPL];
    #pragma unroll
    for (int i = 0; i < CPL; ++i) acc[i] = 0.f;
    float wsl = 0.f;
    #pragma unroll
    for (int rp = 0; rp < ROWS_PW / 2; ++rp) {
        const int r = r0 + rp * 2 + h;
        const uint4* dp = (const uint4*)(f16 + (row0 + r) * D_ + s * CPL);
        uint4 u0 = dp[0], u1 = dp[1], u2 = dp[2];
        float f[CPL];
        unpack8(u0, f); unpack8(u1, f + 8); unpack8(u2, f + 16);
        float dot = 0.f;
        #pragma unroll
        for (int i = 0; i < CPL; ++i) dot = fmaf(f[i], se[i], dot);
        dot = half_sum(dot);
        float rs  = rsal[rbase + r];
        float sv  = sal[rbase + r];
        float m   = mask[rbase + r];
        float sim = dot * rs;
        float wr  = (sim > 0.5f) ? (sim * m) : 0.f;
        float nm  = m * (1.0f - fminf(fmaxf(sim, 0.f), 1.f));
        if (s == 0) { mask[rbase + r] = nm; s_msal[r] = sv * nm; s_salL[r] = sv; }
        wsl += wr;
        #pragma unroll
        for (int i = 0; i < CPL; ++i) acc[i] = fmaf(wr, f[i], acc[i]);
    }
    wsl += __shfl_xor(wsl, 32);
    #pragma unroll
    for (int i = 0; i < CPL; ++i) acc[i] += __shfl_xor(acc[i], 32);
    if (h == 0) {
        float4* rw = (float4*)(s_red + wave * D_ + s * CPL);
        #pragma unroll
        for (int q = 0; q < 6; ++q) {
            float4 v;
            v.x = acc[q*4+0]; v.y = acc[q*4+1]; v.z = acc[q*4+2]; v.w = acc[q*4+3];
            rw[q] = v;
        }
    }
    if (lane == 0) s_wsumW[wave] = wsl;
    __syncthreads();
    #pragma unroll
    for (int it = 0; it < 3; ++it) {
        const int c = it * THR + tid;
        float sm = s_red[c] + s_red[D_ + c] + s_red[2*D_ + c] + s_red[3*D_ + c];
        num[((size_t)b * SLABS + g) * D_ + c] = sm;
    }
    if (tid == 0)
        wsum[b*SLABS+g] = s_wsumW[0] + s_wsumW[1] + s_wsumW[2] + s_wsumW[3];
    if (wave == 0) {
        float v  = (lane < ROWS_PB) ? s_msal[lane] : -INFINITY;
        float sv = (lane < ROWS_PB) ? s_salL[lane] : 0.f;
        int   i  = (lane < ROWS_PB) ? (g * ROWS_PB + lane) : 0x7fffffff;
        #pragma unroll
        for (int off = 32; off; off >>= 1) {
            float ov = __shfl_xor(v, off);
            float osv = __shfl_xor(sv, off);
            int   oi = __shfl_xor(i, off);
            if (ov > v || (ov == v && oi < i)) { v = ov; sv = osv; i = oi; }
        }
        if (lane == 0) { argv[b*SLABS+g] = v; args[b*SLABS+g] = sv; argi[b*SLABS+g] = i; }
    }
}

__global__ __launch_bounds__(192)
void k_out(const float* __restrict__ feat, const float* __restrict__ num,
           const float* __restrict__ wsumA, const float* __restrict__ argv,
           const float* __restrict__ args, const int* __restrict__ argi,
           float* __restrict__ sel, float* __restrict__ out, int t) {
    const int b = blockIdx.x >> 2, q = blockIdx.x & 3;
    const int tid = threadIdx.x, lane = tid & 63;
    __shared__ float s_rsel;
    __shared__ int   s_idx;
    __shared__ float s_ws;
    if (tid < 64) {
        float v  = (lane < SLABS) ? argv[b*SLABS + lane] : -INFINITY;
        float sv = (lane < SLABS) ? args[b*SLABS + lane] : 0.f;
        int   i  = (lane < SLABS) ? argi[b*SLABS + lane] : 0x7fffffff;
        float w  = (lane < SLABS) ? wsumA[b*SLABS + lane] : 0.f;
        #pragma unroll
        for (int off = 32; off; off >>= 1) {
            float ov = __shfl_xor(v, off);
            float osv = __shfl_xor(sv, off);
            int   oi = __shfl_xor(i, off);
            w += __shfl_xor(w, off);
            if (ov > v || (ov == v && oi < i)) { v = ov; sv = osv; i = oi; }
        }
        if (lane == 0) { s_idx = i; s_rsel = 1.0f / fmaxf(sv, 1e-12f); s_ws = w; }
    }
    __syncthreads();
    const int c = q * 192 + tid;
    if (t >= 0) {
        float sm = 0.f;
        #pragma unroll 8
        for (int g = 0; g < SLABS; ++g)
            sm += num[((size_t)b * SLABS + g) * D_ + c];
        out[((size_t)b * T_ + t) * D_ + c] = sm / (s_ws + 1e-8f);
    }
    sel[(size_t)b * D_ + c] = feat[((size_t)b * N_ + s_idx) * D_ + c] * s_rsel;
}

extern "C" void kernel_launch(void* const* d_in, const int* in_sizes, int n_in,
                              void* d_out, int out_size, void* d_ws, size_t ws_size,
                              hipStream_t stream) {
    const float* feat = (const float*)d_in[0];
    float* out = (float*)d_out;
    (void)in_sizes; (void)n_in; (void)out_size;

    const size_t n_sal  = (size_t)B_ * N_;
    const size_t n_arg  = (size_t)B_ * SLABS;
    const size_t n_sel  = (size_t)B_ * D_;
    const size_t n_num  = (size_t)B_ * SLABS * D_;
    const size_t n_f16  = (size_t)B_ * N_ * D_;
    const size_t n_G    = (size_t)B_ * N_ * N_;
    const size_t n_wbuf = (size_t)B_ * T_ * N_;
    const size_t n_part = (size_t)B_ * 4 * T_ * D_;

    const size_t f16_bytes = (n_f16 * sizeof(ushort) + 255) & ~(size_t)255;

    const size_t need_gram = f16_bytes
        + (n_G + n_wbuf + n_part + 3*n_sal + (size_t)B_*T_ + 3*n_arg) * sizeof(float) + 4096;
    const size_t need_mk = f16_bytes
        + (3*n_sal + 4*n_arg + n_sel + n_num) * sizeof(float) + 1024;

    if (ws_size >= need_gram) {
        char* base = (char*)d_ws;
        ushort* f16 = (ushort*)base;
        float* p = (float*)(base + f16_bytes);
        float* G     = p;        p += n_G;
        float* wbuf  = p;        p += n_wbuf;
        float* part  = p;        p += n_part;
        float* sal   = p;        p += n_sal;
        float* rsal  = p;        p += n_sal;
        float* mask  = p;        p += n_sal;
        float* wsum  = p;        p += (size_t)B_ * T_;
        float* argvD = p;        p += n_arg;
        float* argsD = p;        p += n_arg;
        int*   argiD = (int*)p;  p += n_arg;

        k_sal16v<<<B_*SLABS, THR, 0, stream>>>(feat, f16, sal, rsal, mask,
                                               argvD, argsD, argiD);
        k_gram<<<B_*64, THR, 0, stream>>>(f16, G);
        k_slots<<<B_, THR, 0, stream>>>(G, sal, rsal, wbuf, wsum);
        k_wf<<<B_*4, THR, 0, stream>>>(f16, wbuf, part);
        k_red<<<B_*T_, THR, 0, stream>>>(part, wsum, out);
        return;
    }

    if (ws_size >= need_mk) {
        char* base = (char*)d_ws;
        ushort* f16 = (ushort*)base;
        float* p = (float*)(base + f16_bytes);
        float* sal  = p;            p += n_sal;
        float* rsal = p;            p += n_sal;
        float* mask = p;            p += n_sal;
        float* argv = p;            p += n_arg;
        float* args = p;            p += n_arg;
        int*   argi = (int*)p;      p += n_arg;
        float* wsum = p;            p += n_arg;
        float* sel  = p;            p += n_sel;
        float* num  = p;            p += n_num;

        k_sal16v<<<B_*SLABS, THR, 0, stream>>>(feat, f16, sal, rsal, mask, argv, args, argi);
        k_out<<<B_*4, 192, 0, stream>>>(feat, num, wsum, argv, args, argi, sel, out, -1);
        for (int t = 0; t < T_; ++t) {
            k_fusedv<<<B_*SLABS, THR, 0, stream>>>(f16, sel, sal, rsal, mask,
                                                   num, wsum, argv, args, argi);
            k_out<<<B_*4, 192, 0, stream>>>(feat, num, wsum, argv, args, argi, sel, out, t);
        }
        return;
    }
}

// Round 8
// 279.964 us; speedup vs baseline: 1.7367x; 1.5401x over previous
//
#include <hip/hip_runtime.h>
#include <hip/hip_fp16.h>
#include <math.h>

#define B_      64
#define N_      1024
#define D_      768
#define T_      16
#define SLABS   32
#define ROWS_PB 32
#define ROWS_PW 8
#define THR     256
#define CPL     24
#define NTILE   36          // upper-triangle 8x8 tile grid
#define WFG     8           // k_wf row groups

typedef _Float16 half8 __attribute__((ext_vector_type(8)));
typedef float    f32x4 __attribute__((ext_vector_type(4)));

__device__ __forceinline__ float wave_sum(float v) {
    #pragma unroll
    for (int off = 32; off; off >>= 1) v += __shfl_xor(v, off);
    return v;
}
__device__ __forceinline__ float half_sum(float v) {
    #pragma unroll
    for (int off = 16; off; off >>= 1) v += __shfl_xor(v, off);
    return v;
}
__device__ __forceinline__ unsigned pack2(float a, float b) {
    __half2 h = __float22half2_rn(make_float2(a, b));
    return *(unsigned*)&h;
}
__device__ __forceinline__ void unpack8(uint4 u, float* f) {
    __half2 h; float2 q;
    h = *(__half2*)&u.x; q = __half22float2(h); f[0] = q.x; f[1] = q.y;
    h = *(__half2*)&u.y; q = __half22float2(h); f[2] = q.x; f[3] = q.y;
    h = *(__half2*)&u.z; q = __half22float2(h); f[4] = q.x; f[5] = q.y;
    h = *(__half2*)&u.w; q = __half22float2(h); f[6] = q.x; f[7] = q.y;
}

// ---------------- pass 0: saliency + f16 pack ----------------
__global__ __launch_bounds__(THR)
void k_sal16v(const float* __restrict__ feat, ushort* __restrict__ f16,
              float* __restrict__ sal, float* __restrict__ rsal,
              float* __restrict__ mask, float* __restrict__ argv,
              float* __restrict__ args, int* __restrict__ argi) {
    const int blk = blockIdx.x, b = blk >> 5, g = blk & 31;
    const int tid = threadIdx.x, wave = tid >> 6, lane = tid & 63;
    const int h = lane >> 5, s = lane & 31;
    __shared__ float s_sal[ROWS_PB];

    const size_t row0 = (size_t)b * N_ + (size_t)g * ROWS_PB;
    const int r0 = wave * ROWS_PW;

    #pragma unroll
    for (int rp = 0; rp < ROWS_PW / 2; ++rp) {
        const int r = r0 + rp * 2 + h;
        const float4* fp4 = (const float4*)(feat + (row0 + r) * D_ + s * CPL);
        float4 a0 = fp4[0], a1 = fp4[1], a2 = fp4[2], a3 = fp4[3], a4 = fp4[4], a5 = fp4[5];
        uint4 w0, w1, w2;
        w0.x = pack2(a0.x, a0.y); w0.y = pack2(a0.z, a0.w);
        w0.z = pack2(a1.x, a1.y); w0.w = pack2(a1.z, a1.w);
        w1.x = pack2(a2.x, a2.y); w1.y = pack2(a2.z, a2.w);
        w1.z = pack2(a3.x, a3.y); w1.w = pack2(a3.z, a3.w);
        w2.x = pack2(a4.x, a4.y); w2.y = pack2(a4.z, a4.w);
        w2.z = pack2(a5.x, a5.y); w2.w = pack2(a5.z, a5.w);
        uint4* wp = (uint4*)(f16 + (row0 + r) * D_ + s * CPL);
        wp[0] = w0; wp[1] = w1; wp[2] = w2;

        float ss = a0.x*a0.x + a0.y*a0.y + a0.z*a0.z + a0.w*a0.w
                 + a1.x*a1.x + a1.y*a1.y + a1.z*a1.z + a1.w*a1.w
                 + a2.x*a2.x + a2.y*a2.y + a2.z*a2.z + a2.w*a2.w
                 + a3.x*a3.x + a3.y*a3.y + a3.z*a3.z + a3.w*a3.w
                 + a4.x*a4.x + a4.y*a4.y + a4.z*a4.z + a4.w*a4.w
                 + a5.x*a5.x + a5.y*a5.y + a5.z*a5.z + a5.w*a5.w;
        ss = half_sum(ss);
        if (s == 0) s_sal[r] = sqrtf(ss);
    }
    __syncthreads();

    const int rg = b * N_ + g * ROWS_PB;
    if (tid < ROWS_PB) {
        float n = s_sal[tid];
        sal[rg + tid]  = n;
        rsal[rg + tid] = 1.0f / fmaxf(n, 1e-12f);
        mask[rg + tid] = 1.0f;
    }
    if (wave == 0) {
        float v  = (lane < ROWS_PB) ? s_sal[lane] : -INFINITY;
        float sv = v;
        int   i  = (lane < ROWS_PB) ? (g * ROWS_PB + lane) : 0x7fffffff;
        #pragma unroll
        for (int off = 32; off; off >>= 1) {
            float ov = __shfl_xor(v, off);
            float osv = __shfl_xor(sv, off);
            int   oi = __shfl_xor(i, off);
            if (ov > v || (ov == v && oi < i)) { v = ov; sv = osv; i = oi; }
        }
        if (lane == 0) { argv[b*SLABS+g] = v; args[b*SLABS+g] = sv; argi[b*SLABS+g] = i; }
    }
}

// ---------------- Gram GEMM (upper-triangle tiles, XCD-grouped) ----------------
// grid = B_ * NTILE. xcd = bid%8, slot = bid/8; batch = xcd + 8*(slot/NTILE);
// tile = slot%NTILE decoded to (trow<=tcol). Only upper tiles written.
__global__ __launch_bounds__(THR)
void k_gram(const ushort* __restrict__ f16, float* __restrict__ G) {
    const int bid = blockIdx.x;
    const int xcd = bid & 7, slot = bid >> 3;
    const int batch = xcd + 8 * (slot / NTILE);
    int u = slot % NTILE;
    int trow = 0, cnt = 8;
    while (u >= cnt) { u -= cnt; --cnt; ++trow; }
    const int tcol = trow + u;

    const int tid = threadIdx.x, wave = tid >> 6, lane = tid & 63;
    const int wr = wave >> 1, wc = wave & 1;

    __shared__ __align__(16) ushort lA[128 * 64];
    __shared__ __align__(16) ushort lB[128 * 64];

    const ushort* Fb = f16 + (size_t)batch * N_ * D_;
    const int row0 = trow * 128, col0 = tcol * 128;

    f32x4 acc[4][4];
    #pragma unroll
    for (int i = 0; i < 4; ++i)
        #pragma unroll
        for (int j = 0; j < 4; ++j)
            acc[i][j] = (f32x4){0.f, 0.f, 0.f, 0.f};

    for (int k0 = 0; k0 < D_; k0 += 64) {
        #pragma unroll
        for (int i = 0; i < 4; ++i) {
            const int d  = i * THR + tid;
            const int r  = d >> 3;
            const int kc = (d & 7) ^ (r & 7);
            const uint4 va = *(const uint4*)(Fb + (size_t)(row0 + r) * D_ + k0 + kc * 8);
            *(uint4*)(lA + (size_t)d * 8) = va;
            const uint4 vb = *(const uint4*)(Fb + (size_t)(col0 + r) * D_ + k0 + kc * 8);
            *(uint4*)(lB + (size_t)d * 8) = vb;
        }
        __syncthreads();

        #pragma unroll
        for (int ks = 0; ks < 2; ++ks) {
            half8 af[4], bf[4];
            #pragma unroll
            for (int fr = 0; fr < 4; ++fr) {
                const int rl = wr * 64 + fr * 16 + (lane & 15);
                const int kch = ks * 4 + (lane >> 4);
                af[fr] = *(const half8*)(lA + rl * 64 + ((kch ^ (rl & 7)) * 8));
            }
            #pragma unroll
            for (int fc = 0; fc < 4; ++fc) {
                const int cl = wc * 64 + fc * 16 + (lane & 15);
                const int kch = ks * 4 + (lane >> 4);
                bf[fc] = *(const half8*)(lB + cl * 64 + ((kch ^ (cl & 7)) * 8));
            }
            #pragma unroll
            for (int fr = 0; fr < 4; ++fr)
                #pragma unroll
                for (int fc = 0; fc < 4; ++fc)
                    acc[fr][fc] = __builtin_amdgcn_mfma_f32_16x16x32_f16(
                        af[fr], bf[fc], acc[fr][fc], 0, 0, 0);
        }
        __syncthreads();
    }

    float* Gb = G + ((size_t)batch << 20);
    #pragma unroll
    for (int fr = 0; fr < 4; ++fr) {
        #pragma unroll
        for (int fc = 0; fc < 4; ++fc) {
            const int rbase = row0 + wr * 64 + fr * 16 + (lane >> 4) * 4;
            const int c     = col0 + wc * 64 + fc * 16 + (lane & 15);
            #pragma unroll
            for (int q = 0; q < 4; ++q)
                Gb[(size_t)(rbase + q) * N_ + c] = acc[fr][fc][q];
        }
    }
}

// ---------------- slot loop: selection + mask + weights from (upper) G ----------------
__global__ __launch_bounds__(THR)
void k_slots(const float* __restrict__ G, const float* __restrict__ sal,
             const float* __restrict__ rsal, float* __restrict__ wbuf,
             float* __restrict__ wsum) {
    const int b = blockIdx.x, tid = threadIdx.x, wave = tid >> 6, lane = tid & 63;

    __shared__ float s_sal[N_], s_rsal[N_], s_mask[N_], s_msal[N_];
    __shared__ float s_av[4], s_wv[4];
    __shared__ int   s_ai[4];
    __shared__ int   s_idx;
    __shared__ float s_rsidx;

    #pragma unroll
    for (int k = 0; k < 4; ++k) {
        const int n = tid + k * THR;
        float sv = sal[b * N_ + n];
        s_sal[n]  = sv;
        s_rsal[n] = rsal[b * N_ + n];
        s_mask[n] = 1.0f;
        s_msal[n] = sv;
    }
    __syncthreads();

    const float* Gb = G + ((size_t)b << 20);

    for (int t = 0; t < T_; ++t) {
        {
            float v = -INFINITY; int i = 0x7fffffff;
            #pragma unroll
            for (int k = 0; k < 4; ++k) {
                const int n = tid + k * THR;
                float x = s_msal[n];
                if (x > v || (x == v && n < i)) { v = x; i = n; }
            }
            #pragma unroll
            for (int off = 32; off; off >>= 1) {
                float ov = __shfl_xor(v, off);
                int   oi = __shfl_xor(i, off);
                if (ov > v || (ov == v && oi < i)) { v = ov; i = oi; }
            }
            if (lane == 0) { s_av[wave] = v; s_ai[wave] = i; }
        }
        __syncthreads();
        if (tid == 0) {
            float v = s_av[0]; int i = s_ai[0];
            #pragma unroll
            for (int w = 1; w < 4; ++w) {
                float ov = s_av[w]; int oi = s_ai[w];
                if (ov > v || (ov == v && oi < i)) { v = ov; i = oi; }
            }
            s_idx = i;
            s_rsidx = s_rsal[i];
        }
        __syncthreads();

        const int idx = s_idx;
        const float rsi = s_rsidx;

        float wloc = 0.f;
        #pragma unroll
        for (int k = 0; k < 4; ++k) {
            const int n = tid + k * THR;
            float gv  = (n >= idx) ? Gb[(size_t)idx * N_ + n]
                                   : Gb[(size_t)n * N_ + idx];   // symmetric mirror
            float sim = gv * s_rsal[n] * rsi;
            float m   = s_mask[n];
            float w   = (sim > 0.5f) ? (sim * m) : 0.f;
            float nm  = m * (1.0f - fminf(fmaxf(sim, 0.f), 1.f));
            s_mask[n] = nm;
            s_msal[n] = s_sal[n] * nm;
            wbuf[((size_t)(b * T_ + t)) * N_ + n] = w;
            wloc += w;
        }
        wloc = wave_sum(wloc);
        if (lane == 0) s_wv[wave] = wloc;
        __syncthreads();
        if (tid == 0)
            wsum[b * T_ + t] = s_wv[0] + s_wv[1] + s_wv[2] + s_wv[3];
        __syncthreads();
    }
}

// ---------------- W*F partials: WFG row-groups per batch ----------------
__global__ __launch_bounds__(THR)
void k_wf(const ushort* __restrict__ f16, const float* __restrict__ wbuf,
          float* __restrict__ part) {
    const int bid = blockIdx.x, b = bid >> 3, rg = bid & 7;
    const int tid = threadIdx.x;
    const int RPG = N_ / WFG;   // 128 rows per group

    __shared__ float s_w[T_ * (N_ / WFG)];   // 16 x 128 = 8 KiB

    for (int idx = tid; idx < T_ * RPG; idx += THR) {
        const int t = idx / RPG, r = idx % RPG;
        s_w[idx] = wbuf[((size_t)(b * T_ + t)) * N_ + rg * RPG + r];
    }
    __syncthreads();

    float acc[T_][3];
    #pragma unroll
    for (int t = 0; t < T_; ++t) { acc[t][0] = 0.f; acc[t][1] = 0.f; acc[t][2] = 0.f; }

    const _Float16* Fb = (const _Float16*)(f16 + (size_t)b * N_ * D_);
    for (int r = 0; r < RPG; ++r) {
        const _Float16* row = Fb + (size_t)(rg * RPG + r) * D_;
        const float f0 = (float)row[tid];
        const float f1 = (float)row[tid + 256];
        const float f2 = (float)row[tid + 512];
        const float* wr = s_w + r;
        #pragma unroll
        for (int t = 0; t < T_; ++t) {
            const float w = wr[t * RPG];
            acc[t][0] = fmaf(w, f0, acc[t][0]);
            acc[t][1] = fmaf(w, f1, acc[t][1]);
            acc[t][2] = fmaf(w, f2, acc[t][2]);
        }
    }

    float* pb = part + (((size_t)(b * WFG + rg)) * T_) * D_;
    #pragma unroll
    for (int t = 0; t < T_; ++t) {
        pb[(size_t)t * D_ + tid]       = acc[t][0];
        pb[(size_t)t * D_ + tid + 256] = acc[t][1];
        pb[(size_t)t * D_ + tid + 512] = acc[t][2];
    }
}

// ---------------- final reduce + normalize ----------------
__global__ __launch_bounds__(THR)
void k_red(const float* __restrict__ part, const float* __restrict__ wsum,
           float* __restrict__ out) {
    const int bid = blockIdx.x, b = bid >> 4, t = bid & 15;
    const int tid = threadIdx.x;
    const float den = wsum[b * T_ + t] + 1e-8f;
    #pragma unroll
    for (int j = 0; j < 3; ++j) {
        const int c = tid + j * 256;
        float s = 0.f;
        #pragma unroll
        for (int rg = 0; rg < WFG; ++rg)
            s += part[(((size_t)(b * WFG + rg)) * T_ + t) * D_ + c];
        out[((size_t)(b * T_ + t)) * D_ + c] = s / den;
    }
}

// ================= fallback: r6 streaming path =================
__global__ __launch_bounds__(THR)
void k_fusedv(const ushort* __restrict__ f16, const float* __restrict__ sel,
              const float* __restrict__ sal, const float* __restrict__ rsal,
              float* __restrict__ mask, float* __restrict__ num,
              float* __restrict__ wsum, float* __restrict__ argv,
              float* __restrict__ args, int* __restrict__ argi) {
    const int blk = blockIdx.x, b = blk >> 5, g = blk & 31;
    const int tid = threadIdx.x, wave = tid >> 6, lane = tid & 63;
    const int h = lane >> 5, s = lane & 31;
    __shared__ __align__(16) float s_red[4 * D_];
    __shared__ float s_wsumW[4];
    __shared__ float s_msal[ROWS_PB];
    __shared__ float s_salL[ROWS_PB];
    const size_t row0 = (size_t)b * N_ + (size_t)g * ROWS_PB;
    const int rbase = b * N_ + g * ROWS_PB;
    const int r0 = wave * ROWS_PW;
    float se[CPL];
    {
        const float4* sp = (const float4*)(sel + (size_t)b * D_ + s * CPL);
        #pragma unroll
        for (int q = 0; q < 6; ++q) {
            float4 v = sp[q];
            se[q*4+0] = v.x; se[q*4+1] = v.y; se[q*4+2] = v.z; se[q*4+3] = v.w;
        }
    }
    float acc[CPL];
    #pragma unroll
    for (int i = 0; i < CPL; ++i) acc[i] = 0.f;
    float wsl = 0.f;
    #pragma unroll
    for (int rp = 0; rp < ROWS_PW / 2; ++rp) {
        const int r = r0 + rp * 2 + h;
        const uint4* dp = (const uint4*)(f16 + (row0 + r) * D_ + s * CPL);
        uint4 u0 = dp[0], u1 = dp[1], u2 = dp[2];
        float f[CPL];
        unpack8(u0, f); unpack8(u1, f + 8); unpack8(u2, f + 16);
        float dot = 0.f;
        #pragma unroll
        for (int i = 0; i < CPL; ++i) dot = fmaf(f[i], se[i], dot);
        dot = half_sum(dot);
        float rs  = rsal[rbase + r];
        float sv  = sal[rbase + r];
        float m   = mask[rbase + r];
        float sim = dot * rs;
        float wr  = (sim > 0.5f) ? (sim * m) : 0.f;
        float nm  = m * (1.0f - fminf(fmaxf(sim, 0.f), 1.f));
        if (s == 0) { mask[rbase + r] = nm; s_msal[r] = sv * nm; s_salL[r] = sv; }
        wsl += wr;
        #pragma unroll
        for (int i = 0; i < CPL; ++i) acc[i] = fmaf(wr, f[i], acc[i]);
    }
    wsl += __shfl_xor(wsl, 32);
    #pragma unroll
    for (int i = 0; i < CPL; ++i) acc[i] += __shfl_xor(acc[i], 32);
    if (h == 0) {
        float4* rw = (float4*)(s_red + wave * D_ + s * CPL);
        #pragma unroll
        for (int q = 0; q < 6; ++q) {
            float4 v;
            v.x = acc[q*4+0]; v.y = acc[q*4+1]; v.z = acc[q*4+2]; v.w = acc[q*4+3];
            rw[q] = v;
        }
    }
    if (lane == 0) s_wsumW[wave] = wsl;
    __syncthreads();
    #pragma unroll
    for (int it = 0; it < 3; ++it) {
        const int c = it * THR + tid;
        float sm = s_red[c] + s_red[D_ + c] + s_red[2*D_ + c] + s_red[3*D_ + c];
        num[((size_t)b * SLABS + g) * D_ + c] = sm;
    }
    if (tid == 0)
        wsum[b*SLABS+g] = s_wsumW[0] + s_wsumW[1] + s_wsumW[2] + s_wsumW[3];
    if (wave == 0) {
        float v  = (lane < ROWS_PB) ? s_msal[lane] : -INFINITY;
        float sv = (lane < ROWS_PB) ? s_salL[lane] : 0.f;
        int   i  = (lane < ROWS_PB) ? (g * ROWS_PB + lane) : 0x7fffffff;
        #pragma unroll
        for (int off = 32; off; off >>= 1) {
            float ov = __shfl_xor(v, off);
            float osv = __shfl_xor(sv, off);
            int   oi = __shfl_xor(i, off);
            if (ov > v || (ov == v && oi < i)) { v = ov; sv = osv; i = oi; }
        }
        if (lane == 0) { argv[b*SLABS+g] = v; args[b*SLABS+g] = sv; argi[b*SLABS+g] = i; }
    }
}

__global__ __launch_bounds__(192)
void k_out(const float* __restrict__ feat, const float* __restrict__ num,
           const float* __restrict__ wsumA, const float* __restrict__ argv,
           const float* __restrict__ args, const int* __restrict__ argi,
           float* __restrict__ sel, float* __restrict__ out, int t) {
    const int b = blockIdx.x >> 2, q = blockIdx.x & 3;
    const int tid = threadIdx.x, lane = tid & 63;
    __shared__ float s_rsel;
    __shared__ int   s_idx;
    __shared__ float s_ws;
    if (tid < 64) {
        float v  = (lane < SLABS) ? argv[b*SLABS + lane] : -INFINITY;
        float sv = (lane < SLABS) ? args[b*SLABS + lane] : 0.f;
        int   i  = (lane < SLABS) ? argi[b*SLABS + lane] : 0x7fffffff;
        float w  = (lane < SLABS) ? wsumA[b*SLABS + lane] : 0.f;
        #pragma unroll
        for (int off = 32; off; off >>= 1) {
            float ov = __shfl_xor(v, off);
            float osv = __shfl_xor(sv, off);
            int   oi = __shfl_xor(i, off);
            w += __shfl_xor(w, off);
            if (ov > v || (ov == v && oi < i)) { v = ov; sv = osv; i = oi; }
        }
        if (lane == 0) { s_idx = i; s_rsel = 1.0f / fmaxf(sv, 1e-12f); s_ws = w; }
    }
    __syncthreads();
    const int c = q * 192 + tid;
    if (t >= 0) {
        float sm = 0.f;
        #pragma unroll 8
        for (int g = 0; g < SLABS; ++g)
            sm += num[((size_t)b * SLABS + g) * D_ + c];
        out[((size_t)b * T_ + t) * D_ + c] = sm / (s_ws + 1e-8f);
    }
    sel[(size_t)b * D_ + c] = feat[((size_t)b * N_ + s_idx) * D_ + c] * s_rsel;
}

extern "C" void kernel_launch(void* const* d_in, const int* in_sizes, int n_in,
                              void* d_out, int out_size, void* d_ws, size_t ws_size,
                              hipStream_t stream) {
    const float* feat = (const float*)d_in[0];
    float* out = (float*)d_out;
    (void)in_sizes; (void)n_in; (void)out_size;

    const size_t n_sal  = (size_t)B_ * N_;
    const size_t n_arg  = (size_t)B_ * SLABS;
    const size_t n_sel  = (size_t)B_ * D_;
    const size_t n_num  = (size_t)B_ * SLABS * D_;
    const size_t n_f16  = (size_t)B_ * N_ * D_;
    const size_t n_G    = (size_t)B_ * N_ * N_;
    const size_t n_wbuf = (size_t)B_ * T_ * N_;
    const size_t n_part = (size_t)B_ * WFG * T_ * D_;

    const size_t f16_bytes = (n_f16 * sizeof(ushort) + 255) & ~(size_t)255;

    const size_t need_gram = f16_bytes
        + (n_G + n_wbuf + n_part + 3*n_sal + (size_t)B_*T_ + 3*n_arg) * sizeof(float) + 4096;
    const size_t need_mk = f16_bytes
        + (3*n_sal + 4*n_arg + n_sel + n_num) * sizeof(float) + 1024;

    if (ws_size >= need_gram) {
        char* base = (char*)d_ws;
        ushort* f16 = (ushort*)base;
        float* p = (float*)(base + f16_bytes);
        float* G     = p;        p += n_G;
        float* wbuf  = p;        p += n_wbuf;
        float* part  = p;        p += n_part;
        float* sal   = p;        p += n_sal;
        float* rsal  = p;        p += n_sal;
        float* mask  = p;        p += n_sal;
        float* wsum  = p;        p += (size_t)B_ * T_;
        float* argvD = p;        p += n_arg;
        float* argsD = p;        p += n_arg;
        int*   argiD = (int*)p;  p += n_arg;

        k_sal16v<<<B_*SLABS, THR, 0, stream>>>(feat, f16, sal, rsal, mask,
                                               argvD, argsD, argiD);
        k_gram<<<B_*NTILE, THR, 0, stream>>>(f16, G);
        k_slots<<<B_, THR, 0, stream>>>(G, sal, rsal, wbuf, wsum);
        k_wf<<<B_*WFG, THR, 0, stream>>>(f16, wbuf, part);
        k_red<<<B_*T_, THR, 0, stream>>>(part, wsum, out);
        return;
    }

    if (ws_size >= need_mk) {
        char* base = (char*)d_ws;
        ushort* f16 = (ushort*)base;
        float* p = (float*)(base + f16_bytes);
        float* sal  = p;            p += n_sal;
        float* rsal = p;            p += n_sal;
        float* mask = p;            p += n_sal;
        float* argv = p;            p += n_arg;
        float* args = p;            p += n_arg;
        int*   argi = (int*)p;      p += n_arg;
        float* wsum = p;            p += n_arg;
        float* sel  = p;            p += n_sel;
        float* num  = p;            p += n_num;

        k_sal16v<<<B_*SLABS, THR, 0, stream>>>(feat, f16, sal, rsal, mask, argv, args, argi);
        k_out<<<B_*4, 192, 0, stream>>>(feat, num, wsum, argv, args, argi, sel, out, -1);
        for (int t = 0; t < T_; ++t) {
            k_fusedv<<<B_*SLABS, THR, 0, stream>>>(f16, sel, sal, rsal, mask,
                                                   num, wsum, argv, args, argi);
            k_out<<<B_*4, 192, 0, stream>>>(feat, num, wsum, argv, args, argi, sel, out, t);
        }
        return;
    }
}

// Round 9
// 254.677 us; speedup vs baseline: 1.9091x; 1.0993x over previous
//
#include <hip/hip_runtime.h>
#include <hip/hip_fp16.h>
#include <math.h>

#define B_      64
#define N_      1024
#define D_      768
#define T_      16
#define SLABS   32
#define ROWS_PB 32
#define ROWS_PW 8
#define THR     256
#define CPL     24
#define NTILE   36          // upper-triangle 8x8 tile grid
#define WFG     8           // k_wf row groups
#define WFTHR   192         // k_wf threads (4 cols each)

typedef _Float16 half8 __attribute__((ext_vector_type(8)));
typedef float    f32x4 __attribute__((ext_vector_type(4)));

__device__ __forceinline__ float wave_sum(float v) {
    #pragma unroll
    for (int off = 32; off; off >>= 1) v += __shfl_xor(v, off);
    return v;
}
__device__ __forceinline__ float half_sum(float v) {
    #pragma unroll
    for (int off = 16; off; off >>= 1) v += __shfl_xor(v, off);
    return v;
}
__device__ __forceinline__ unsigned pack2(float a, float b) {
    __half2 h = __float22half2_rn(make_float2(a, b));
    return *(unsigned*)&h;
}
__device__ __forceinline__ void unpack8(uint4 u, float* f) {
    __half2 h; float2 q;
    h = *(__half2*)&u.x; q = __half22float2(h); f[0] = q.x; f[1] = q.y;
    h = *(__half2*)&u.y; q = __half22float2(h); f[2] = q.x; f[3] = q.y;
    h = *(__half2*)&u.z; q = __half22float2(h); f[4] = q.x; f[5] = q.y;
    h = *(__half2*)&u.w; q = __half22float2(h); f[6] = q.x; f[7] = q.y;
}

// async global->LDS, 16B per lane. Per-lane lds ptr must equal
// wave-uniform base + lane*16 (G21): our dest index d = i*THR + wave*64 + lane.
__device__ __forceinline__ void gload_lds16(const void* g, void* l) {
    __builtin_amdgcn_global_load_lds(
        (__attribute__((address_space(1))) void*)(g),
        (__attribute__((address_space(3))) void*)(l), 16, 0, 0);
}

// ---------------- pass 0: saliency + f16 pack ----------------
__global__ __launch_bounds__(THR)
void k_sal16v(const float* __restrict__ feat, ushort* __restrict__ f16,
              float* __restrict__ sal, float* __restrict__ rsal,
              float* __restrict__ mask, float* __restrict__ argv,
              float* __restrict__ args, int* __restrict__ argi) {
    const int blk = blockIdx.x, b = blk >> 5, g = blk & 31;
    const int tid = threadIdx.x, wave = tid >> 6, lane = tid & 63;
    const int h = lane >> 5, s = lane & 31;
    __shared__ float s_sal[ROWS_PB];

    const size_t row0 = (size_t)b * N_ + (size_t)g * ROWS_PB;
    const int r0 = wave * ROWS_PW;

    #pragma unroll
    for (int rp = 0; rp < ROWS_PW / 2; ++rp) {
        const int r = r0 + rp * 2 + h;
        const float4* fp4 = (const float4*)(feat + (row0 + r) * D_ + s * CPL);
        float4 a0 = fp4[0], a1 = fp4[1], a2 = fp4[2], a3 = fp4[3], a4 = fp4[4], a5 = fp4[5];
        uint4 w0, w1, w2;
        w0.x = pack2(a0.x, a0.y); w0.y = pack2(a0.z, a0.w);
        w0.z = pack2(a1.x, a1.y); w0.w = pack2(a1.z, a1.w);
        w1.x = pack2(a2.x, a2.y); w1.y = pack2(a2.z, a2.w);
        w1.z = pack2(a3.x, a3.y); w1.w = pack2(a3.z, a3.w);
        w2.x = pack2(a4.x, a4.y); w2.y = pack2(a4.z, a4.w);
        w2.z = pack2(a5.x, a5.y); w2.w = pack2(a5.z, a5.w);
        uint4* wp = (uint4*)(f16 + (row0 + r) * D_ + s * CPL);
        wp[0] = w0; wp[1] = w1; wp[2] = w2;

        float ss = a0.x*a0.x + a0.y*a0.y + a0.z*a0.z + a0.w*a0.w
                 + a1.x*a1.x + a1.y*a1.y + a1.z*a1.z + a1.w*a1.w
                 + a2.x*a2.x + a2.y*a2.y + a2.z*a2.z + a2.w*a2.w
                 + a3.x*a3.x + a3.y*a3.y + a3.z*a3.z + a3.w*a3.w
                 + a4.x*a4.x + a4.y*a4.y + a4.z*a4.z + a4.w*a4.w
                 + a5.x*a5.x + a5.y*a5.y + a5.z*a5.z + a5.w*a5.w;
        ss = half_sum(ss);
        if (s == 0) s_sal[r] = sqrtf(ss);
    }
    __syncthreads();

    const int rg = b * N_ + g * ROWS_PB;
    if (tid < ROWS_PB) {
        float n = s_sal[tid];
        sal[rg + tid]  = n;
        rsal[rg + tid] = 1.0f / fmaxf(n, 1e-12f);
        mask[rg + tid] = 1.0f;
    }
    if (wave == 0) {
        float v  = (lane < ROWS_PB) ? s_sal[lane] : -INFINITY;
        float sv = v;
        int   i  = (lane < ROWS_PB) ? (g * ROWS_PB + lane) : 0x7fffffff;
        #pragma unroll
        for (int off = 32; off; off >>= 1) {
            float ov = __shfl_xor(v, off);
            float osv = __shfl_xor(sv, off);
            int   oi = __shfl_xor(i, off);
            if (ov > v || (ov == v && oi < i)) { v = ov; sv = osv; i = oi; }
        }
        if (lane == 0) { argv[b*SLABS+g] = v; args[b*SLABS+g] = sv; argi[b*SLABS+g] = i; }
    }
}

// ---------------- Gram GEMM (upper-triangle, XCD-grouped, global_load_lds) ----------------
__global__ __launch_bounds__(THR)
void k_gram(const ushort* __restrict__ f16, float* __restrict__ G) {
    const int bid = blockIdx.x;
    const int xcd = bid & 7, slot = bid >> 3;
    const int batch = xcd + 8 * (slot / NTILE);
    int u = slot % NTILE;
    int trow = 0, cnt = 8;
    while (u >= cnt) { u -= cnt; --cnt; ++trow; }
    const int tcol = trow + u;
    const bool diag = (trow == tcol);

    const int tid = threadIdx.x, wave = tid >> 6, lane = tid & 63;
    const int wr = wave >> 1, wc = wave & 1;

    __shared__ __align__(16) ushort lA[128 * 64];
    __shared__ __align__(16) ushort lB[128 * 64];

    const ushort* Fb = f16 + (size_t)batch * N_ * D_;
    const int row0 = trow * 128, col0 = tcol * 128;

    f32x4 acc[4][4];
    #pragma unroll
    for (int i = 0; i < 4; ++i)
        #pragma unroll
        for (int j = 0; j < 4; ++j)
            acc[i][j] = (f32x4){0.f, 0.f, 0.f, 0.f};

    const ushort* lBr = diag ? lA : lB;   // diag tiles read B from lA

    for (int k0 = 0; k0 < D_; k0 += 64) {
        // stage: linear LDS dest (d = i*THR + wave*64 + lane), pre-swizzled source
        #pragma unroll
        for (int i = 0; i < 4; ++i) {
            const int d  = i * THR + tid;
            const int r  = d >> 3;
            const int kc = (d & 7) ^ (r & 7);
            gload_lds16(Fb + (size_t)(row0 + r) * D_ + k0 + kc * 8, lA + (size_t)d * 8);
            if (!diag)
                gload_lds16(Fb + (size_t)(col0 + r) * D_ + k0 + kc * 8, lB + (size_t)d * 8);
        }
        __syncthreads();

        #pragma unroll
        for (int ks = 0; ks < 2; ++ks) {
            half8 af[4], bf[4];
            #pragma unroll
            for (int fr = 0; fr < 4; ++fr) {
                const int rl = wr * 64 + fr * 16 + (lane & 15);
                const int kch = ks * 4 + (lane >> 4);
                af[fr] = *(const half8*)(lA + rl * 64 + ((kch ^ (rl & 7)) * 8));
            }
            #pragma unroll
            for (int fc = 0; fc < 4; ++fc) {
                const int cl = wc * 64 + fc * 16 + (lane & 15);
                const int kch = ks * 4 + (lane >> 4);
                bf[fc] = *(const half8*)(lBr + cl * 64 + ((kch ^ (cl & 7)) * 8));
            }
            #pragma unroll
            for (int fr = 0; fr < 4; ++fr)
                #pragma unroll
                for (int fc = 0; fc < 4; ++fc)
                    acc[fr][fc] = __builtin_amdgcn_mfma_f32_16x16x32_f16(
                        af[fr], bf[fc], acc[fr][fc], 0, 0, 0);
        }
        __syncthreads();
    }

    float* Gb = G + ((size_t)batch << 20);
    #pragma unroll
    for (int fr = 0; fr < 4; ++fr) {
        #pragma unroll
        for (int fc = 0; fc < 4; ++fc) {
            const int rbase = row0 + wr * 64 + fr * 16 + (lane >> 4) * 4;
            const int c     = col0 + wc * 64 + fc * 16 + (lane & 15);
            #pragma unroll
            for (int q = 0; q < 4; ++q)
                Gb[(size_t)(rbase + q) * N_ + c] = acc[fr][fc][q];
        }
    }
}

// ---------------- slot loop: 1024 threads for latency hiding ----------------
__global__ __launch_bounds__(1024)
void k_slots(const float* __restrict__ G, const float* __restrict__ sal,
             const float* __restrict__ rsal, float* __restrict__ wbuf,
             float* __restrict__ wsum) {
    const int b = blockIdx.x, tid = threadIdx.x, wave = tid >> 6, lane = tid & 63;

    __shared__ float s_sal[N_], s_rsal[N_], s_mask[N_], s_msal[N_];
    __shared__ float s_av[16], s_wv[16];
    __shared__ int   s_ai[16];
    __shared__ int   s_idx;
    __shared__ float s_rsidx;

    {
        const int n = tid;
        float sv = sal[b * N_ + n];
        s_sal[n]  = sv;
        s_rsal[n] = rsal[b * N_ + n];
        s_mask[n] = 1.0f;
        s_msal[n] = sv;
    }
    __syncthreads();

    const float* Gb = G + ((size_t)b << 20);

    for (int t = 0; t < T_; ++t) {
        {
            float v = s_msal[tid]; int i = tid;
            #pragma unroll
            for (int off = 32; off; off >>= 1) {
                float ov = __shfl_xor(v, off);
                int   oi = __shfl_xor(i, off);
                if (ov > v || (ov == v && oi < i)) { v = ov; i = oi; }
            }
            if (lane == 0) { s_av[wave] = v; s_ai[wave] = i; }
        }
        __syncthreads();
        if (tid == 0) {
            float v = s_av[0]; int i = s_ai[0];
            #pragma unroll
            for (int w = 1; w < 16; ++w) {
                float ov = s_av[w]; int oi = s_ai[w];
                if (ov > v || (ov == v && oi < i)) { v = ov; i = oi; }
            }
            s_idx = i;
            s_rsidx = s_rsal[i];
        }
        __syncthreads();

        const int idx = s_idx;
        const float rsi = s_rsidx;

        const int n = tid;
        float gv  = (n >= idx) ? Gb[(size_t)idx * N_ + n]
                               : Gb[(size_t)n * N_ + idx];   // symmetric mirror
        float sim = gv * s_rsal[n] * rsi;
        float m   = s_mask[n];
        float w   = (sim > 0.5f) ? (sim * m) : 0.f;
        float nm  = m * (1.0f - fminf(fmaxf(sim, 0.f), 1.f));
        s_mask[n] = nm;
        s_msal[n] = s_sal[n] * nm;
        wbuf[((size_t)(b * T_ + t)) * N_ + n] = w;
        float wloc = wave_sum(w);
        if (lane == 0) s_wv[wave] = wloc;
        __syncthreads();
        if (tid == 0) {
            float acc = 0.f;
            #pragma unroll
            for (int w2 = 0; w2 < 16; ++w2) acc += s_wv[w2];
            wsum[b * T_ + t] = acc;
        }
        __syncthreads();
    }
}

// ---------------- W*F partials: 192 thr, 4 consecutive cols each (uint2 loads) ----------------
__global__ __launch_bounds__(WFTHR)
void k_wf(const ushort* __restrict__ f16, const float* __restrict__ wbuf,
          float* __restrict__ part) {
    const int bid = blockIdx.x, b = bid >> 3, rg = bid & 7;
    const int tid = threadIdx.x;
    const int RPG = N_ / WFG;   // 128 rows per group

    __shared__ float s_w[T_ * (N_ / WFG)];   // 16 x 128 = 8 KiB

    for (int idx = tid; idx < T_ * RPG; idx += WFTHR) {
        const int t = idx >> 7, r = idx & 127;
        s_w[idx] = wbuf[((size_t)(b * T_ + t)) * N_ + rg * RPG + r];
    }
    __syncthreads();

    float acc[T_][4];
    #pragma unroll
    for (int t = 0; t < T_; ++t) {
        acc[t][0] = 0.f; acc[t][1] = 0.f; acc[t][2] = 0.f; acc[t][3] = 0.f;
    }

    const ushort* Fb = f16 + (size_t)b * N_ * D_;
    for (int r = 0; r < RPG; ++r) {
        const uint2 u = *(const uint2*)(Fb + (size_t)(rg * RPG + r) * D_ + tid * 4);
        __half2 h0 = *(__half2*)&u.x; float2 q0 = __half22float2(h0);
        __half2 h1 = *(__half2*)&u.y; float2 q1 = __half22float2(h1);
        const float f0 = q0.x, f1 = q0.y, f2 = q1.x, f3 = q1.y;
        const float* wr = s_w + r;
        #pragma unroll
        for (int t = 0; t < T_; ++t) {
            const float w = wr[t << 7];
            acc[t][0] = fmaf(w, f0, acc[t][0]);
            acc[t][1] = fmaf(w, f1, acc[t][1]);
            acc[t][2] = fmaf(w, f2, acc[t][2]);
            acc[t][3] = fmaf(w, f3, acc[t][3]);
        }
    }

    float* pb = part + (((size_t)(b * WFG + rg)) * T_) * D_;
    #pragma unroll
    for (int t = 0; t < T_; ++t) {
        float4 v; v.x = acc[t][0]; v.y = acc[t][1]; v.z = acc[t][2]; v.w = acc[t][3];
        *(float4*)(pb + (size_t)t * D_ + tid * 4) = v;
    }
}

// ---------------- final reduce + normalize ----------------
__global__ __launch_bounds__(THR)
void k_red(const float* __restrict__ part, const float* __restrict__ wsum,
           float* __restrict__ out) {
    const int bid = blockIdx.x, b = bid >> 4, t = bid & 15;
    const int tid = threadIdx.x;
    const float den = wsum[b * T_ + t] + 1e-8f;
    #pragma unroll
    for (int j = 0; j < 3; ++j) {
        const int c = tid + j * 256;
        float s = 0.f;
        #pragma unroll
        for (int rg = 0; rg < WFG; ++rg)
            s += part[(((size_t)(b * WFG + rg)) * T_ + t) * D_ + c];
        out[((size_t)(b * T_ + t)) * D_ + c] = s / den;
    }
}

// ================= fallback: r6 streaming path =================
__global__ __launch_bounds__(THR)
void k_fusedv(const ushort* __restrict__ f16, const float* __restrict__ sel,
              const float* __restrict__ sal, const float* __restrict__ rsal,
              float* __restrict__ mask, float* __restrict__ num,
              float* __restrict__ wsum, float* __restrict__ argv,
              float* __restrict__ args, int* __restrict__ argi) {
    const int blk = blockIdx.x, b = blk >> 5, g = blk & 31;
    const int tid = threadIdx.x, wave = tid >> 6, lane = tid & 63;
    const int h = lane >> 5, s = lane & 31;
    __shared__ __align__(16) float s_red[4 * D_];
    __shared__ float s_wsumW[4];
    __shared__ float s_msal[ROWS_PB];
    __shared__ float s_salL[ROWS_PB];
    const size_t row0 = (size_t)b * N_ + (size_t)g * ROWS_PB;
    const int rbase = b * N_ + g * ROWS_PB;
    const int r0 = wave * ROWS_PW;
    float se[CPL];
    {
        const float4* sp = (const float4*)(sel + (size_t)b * D_ + s * CPL);
        #pragma unroll
        for (int q = 0; q < 6; ++q) {
            float4 v = sp[q];
            se[q*4+0] = v.x; se[q*4+1] = v.y; se[q*4+2] = v.z; se[q*4+3] = v.w;
        }
    }
    float acc[CPL];
    #pragma unroll
    for (int i = 0; i < CPL; ++i) acc[i] = 0.f;
    float wsl = 0.f;
    #pragma unroll
    for (int rp = 0; rp < ROWS_PW / 2; ++rp) {
        const int r = r0 + rp * 2 + h;
        const uint4* dp = (const uint4*)(f16 + (row0 + r) * D_ + s * CPL);
        uint4 u0 = dp[0], u1 = dp[1], u2 = dp[2];
        float f[CPL];
        unpack8(u0, f); unpack8(u1, f + 8); unpack8(u2, f + 16);
        float dot = 0.f;
        #pragma unroll
        for (int i = 0; i < CPL; ++i) dot = fmaf(f[i], se[i], dot);
        dot = half_sum(dot);
        float rs  = rsal[rbase + r];
        float sv  = sal[rbase + r];
        float m   = mask[rbase + r];
        float sim = dot * rs;
        float wr  = (sim > 0.5f) ? (sim * m) : 0.f;
        float nm  = m * (1.0f - fminf(fmaxf(sim, 0.f), 1.f));
        if (s == 0) { mask[rbase + r] = nm; s_msal[r] = sv * nm; s_salL[r] = sv; }
        wsl += wr;
        #pragma unroll
        for (int i = 0; i < CPL; ++i) acc[i] = fmaf(wr, f[i], acc[i]);
    }
    wsl += __shfl_xor(wsl, 32);
    #pragma unroll
    for (int i = 0; i < CPL; ++i) acc[i] += __shfl_xor(acc[i], 32);
    if (h == 0) {
        float4* rw = (float4*)(s_red + wave * D_ + s * CPL);
        #pragma unroll
        for (int q = 0; q < 6; ++q) {
            float4 v;
            v.x = acc[q*4+0]; v.y = acc[q*4+1]; v.z = acc[q*4+2]; v.w = acc[q*4+3];
            rw[q] = v;
        }
    }
    if (lane == 0) s_wsumW[wave] = wsl;
    __syncthreads();
    #pragma unroll
    for (int it = 0; it < 3; ++it) {
        const int c = it * THR + tid;
        float sm = s_red[c] + s_red[D_ + c] + s_red[2*D_ + c] + s_red[3*D_ + c];
        num[((size_t)b * SLABS + g) * D_ + c] = sm;
    }
    if (tid == 0)
        wsum[b*SLABS+g] = s_wsumW[0] + s_wsumW[1] + s_wsumW[2] + s_wsumW[3];
    if (wave == 0) {
        float v  = (lane < ROWS_PB) ? s_msal[lane] : -INFINITY;
        float sv = (lane < ROWS_PB) ? s_salL[lane] : 0.f;
        int   i  = (lane < ROWS_PB) ? (g * ROWS_PB + lane) : 0x7fffffff;
        #pragma unroll
        for (int off = 32; off; off >>= 1) {
            float ov = __shfl_xor(v, off);
            float osv = __shfl_xor(sv, off);
            int   oi = __shfl_xor(i, off);
            if (ov > v || (ov == v && oi < i)) { v = ov; sv = osv; i = oi; }
        }
        if (lane == 0) { argv[b*SLABS+g] = v; args[b*SLABS+g] = sv; argi[b*SLABS+g] = i; }
    }
}

__global__ __launch_bounds__(192)
void k_out(const float* __restrict__ feat, const float* __restrict__ num,
           const float* __restrict__ wsumA, const float* __restrict__ argv,
           const float* __restrict__ args, const int* __restrict__ argi,
           float* __restrict__ sel, float* __restrict__ out, int t) {
    const int b = blockIdx.x >> 2, q = blockIdx.x & 3;
    const int tid = threadIdx.x, lane = tid & 63;
    __shared__ float s_rsel;
    __shared__ int   s_idx;
    __shared__ float s_ws;
    if (tid < 64) {
        float v  = (lane < SLABS) ? argv[b*SLABS + lane] : -INFINITY;
        float sv = (lane < SLABS) ? args[b*SLABS + lane] : 0.f;
        int   i  = (lane < SLABS) ? argi[b*SLABS + lane] : 0x7fffffff;
        float w  = (lane < SLABS) ? wsumA[b*SLABS + lane] : 0.f;
        #pragma unroll
        for (int off = 32; off; off >>= 1) {
            float ov = __shfl_xor(v, off);
            float osv = __shfl_xor(sv, off);
            int   oi = __shfl_xor(i, off);
            w += __shfl_xor(w, off);
            if (ov > v || (ov == v && oi < i)) { v = ov; sv = osv; i = oi; }
        }
        if (lane == 0) { s_idx = i; s_rsel = 1.0f / fmaxf(sv, 1e-12f); s_ws = w; }
    }
    __syncthreads();
    const int c = q * 192 + tid;
    if (t >= 0) {
        float sm = 0.f;
        #pragma unroll 8
        for (int g = 0; g < SLABS; ++g)
            sm += num[((size_t)b * SLABS + g) * D_ + c];
        out[((size_t)b * T_ + t) * D_ + c] = sm / (s_ws + 1e-8f);
    }
    sel[(size_t)b * D_ + c] = feat[((size_t)b * N_ + s_idx) * D_ + c] * s_rsel;
}

extern "C" void kernel_launch(void* const* d_in, const int* in_sizes, int n_in,
                              void* d_out, int out_size, void* d_ws, size_t ws_size,
                              hipStream_t stream) {
    const float* feat = (const float*)d_in[0];
    float* out = (float*)d_out;
    (void)in_sizes; (void)n_in; (void)out_size;

    const size_t n_sal  = (size_t)B_ * N_;
    const size_t n_arg  = (size_t)B_ * SLABS;
    const size_t n_sel  = (size_t)B_ * D_;
    const size_t n_num  = (size_t)B_ * SLABS * D_;
    const size_t n_f16  = (size_t)B_ * N_ * D_;
    const size_t n_G    = (size_t)B_ * N_ * N_;
    const size_t n_wbuf = (size_t)B_ * T_ * N_;
    const size_t n_part = (size_t)B_ * WFG * T_ * D_;

    const size_t f16_bytes = (n_f16 * sizeof(ushort) + 255) & ~(size_t)255;

    const size_t need_gram = f16_bytes
        + (n_G + n_wbuf + n_part + 3*n_sal + (size_t)B_*T_ + 3*n_arg) * sizeof(float) + 4096;
    const size_t need_mk = f16_bytes
        + (3*n_sal + 4*n_arg + n_sel + n_num) * sizeof(float) + 1024;

    if (ws_size >= need_gram) {
        char* base = (char*)d_ws;
        ushort* f16 = (ushort*)base;
        float* p = (float*)(base + f16_bytes);
        float* G     = p;        p += n_G;
        float* wbuf  = p;        p += n_wbuf;
        float* part  = p;        p += n_part;
        float* sal   = p;        p += n_sal;
        float* rsal  = p;        p += n_sal;
        float* mask  = p;        p += n_sal;
        float* wsum  = p;        p += (size_t)B_ * T_;
        float* argvD = p;        p += n_arg;
        float* argsD = p;        p += n_arg;
        int*   argiD = (int*)p;  p += n_arg;

        k_sal16v<<<B_*SLABS, THR, 0, stream>>>(feat, f16, sal, rsal, mask,
                                               argvD, argsD, argiD);
        k_gram<<<B_*NTILE, THR, 0, stream>>>(f16, G);
        k_slots<<<B_, 1024, 0, stream>>>(G, sal, rsal, wbuf, wsum);
        k_wf<<<B_*WFG, WFTHR, 0, stream>>>(f16, wbuf, part);
        k_red<<<B_*T_, THR, 0, stream>>>(part, wsum, out);
        return;
    }

    if (ws_size >= need_mk) {
        char* base = (char*)d_ws;
        ushort* f16 = (ushort*)base;
        float* p = (float*)(base + f16_bytes);
        float* sal  = p;            p += n_sal;
        float* rsal = p;            p += n_sal;
        float* mask = p;            p += n_sal;
        float* argv = p;            p += n_arg;
        float* args = p;            p += n_arg;
        int*   argi = (int*)p;      p += n_arg;
        float* wsum = p;            p += n_arg;
        float* sel  = p;            p += n_sel;
        float* num  = p;            p += n_num;

        k_sal16v<<<B_*SLABS, THR, 0, stream>>>(feat, f16, sal, rsal, mask, argv, args, argi);
        k_out<<<B_*4, 192, 0, stream>>>(feat, num, wsum, argv, args, argi, sel, out, -1);
        for (int t = 0; t < T_; ++t) {
            k_fusedv<<<B_*SLABS, THR, 0, stream>>>(f16, sel, sal, rsal, mask,
                                                   num, wsum, argv, args, argi);
            k_out<<<B_*4, 192, 0, stream>>>(feat, num, wsum, argv, args, argi, sel, out, t);
        }
        return;
    }
}

// Round 11
// 237.336 us; speedup vs baseline: 2.0486x; 1.0731x over previous
//
#include <hip/hip_runtime.h>
#include <hip/hip_fp16.h>
#include <math.h>

#define B_      64
#define N_      1024
#define D_      768
#define T_      16
#define SLABS   32
#define ROWS_PB 32
#define ROWS_PW 8
#define THR     256
#define CPL     24
#define NTILE   36          // upper-triangle 8x8 tile grid
#define WFG     8           // k_wf row groups
#define WFTHR   192         // k_wf threads (4 cols each)

typedef _Float16 half8 __attribute__((ext_vector_type(8)));
typedef float    f32x4 __attribute__((ext_vector_type(4)));

__device__ __forceinline__ float wave_sum(float v) {
    #pragma unroll
    for (int off = 32; off; off >>= 1) v += __shfl_xor(v, off);
    return v;
}
__device__ __forceinline__ float half_sum(float v) {
    #pragma unroll
    for (int off = 16; off; off >>= 1) v += __shfl_xor(v, off);
    return v;
}
__device__ __forceinline__ unsigned pack2(float a, float b) {
    __half2 h = __float22half2_rn(make_float2(a, b));
    return *(unsigned*)&h;
}
__device__ __forceinline__ void unpack8(uint4 u, float* f) {
    __half2 h; float2 q;
    h = *(__half2*)&u.x; q = __half22float2(h); f[0] = q.x; f[1] = q.y;
    h = *(__half2*)&u.y; q = __half22float2(h); f[2] = q.x; f[3] = q.y;
    h = *(__half2*)&u.z; q = __half22float2(h); f[4] = q.x; f[5] = q.y;
    h = *(__half2*)&u.w; q = __half22float2(h); f[6] = q.x; f[7] = q.y;
}

// async global->LDS, 16B per lane (dest = wave-uniform base + lane*16, G21)
__device__ __forceinline__ void gload_lds16(const void* g, void* l) {
    __builtin_amdgcn_global_load_lds(
        (__attribute__((address_space(1))) void*)(g),
        (__attribute__((address_space(3))) void*)(l), 16, 0, 0);
}

// ---------------- pass 0: saliency + f16 pack ----------------
__global__ __launch_bounds__(THR)
void k_sal16v(const float* __restrict__ feat, ushort* __restrict__ f16,
              float* __restrict__ sal, float* __restrict__ rsal,
              float* __restrict__ mask, float* __restrict__ argv,
              float* __restrict__ args, int* __restrict__ argi) {
    const int blk = blockIdx.x, b = blk >> 5, g = blk & 31;
    const int tid = threadIdx.x, wave = tid >> 6, lane = tid & 63;
    const int h = lane >> 5, s = lane & 31;
    __shared__ float s_sal[ROWS_PB];

    const size_t row0 = (size_t)b * N_ + (size_t)g * ROWS_PB;
    const int r0 = wave * ROWS_PW;

    #pragma unroll
    for (int rp = 0; rp < ROWS_PW / 2; ++rp) {
        const int r = r0 + rp * 2 + h;
        const float4* fp4 = (const float4*)(feat + (row0 + r) * D_ + s * CPL);
        float4 a0 = fp4[0], a1 = fp4[1], a2 = fp4[2], a3 = fp4[3], a4 = fp4[4], a5 = fp4[5];
        uint4 w0, w1, w2;
        w0.x = pack2(a0.x, a0.y); w0.y = pack2(a0.z, a0.w);
        w0.z = pack2(a1.x, a1.y); w0.w = pack2(a1.z, a1.w);
        w1.x = pack2(a2.x, a2.y); w1.y = pack2(a2.z, a2.w);
        w1.z = pack2(a3.x, a3.y); w1.w = pack2(a3.z, a3.w);
        w2.x = pack2(a4.x, a4.y); w2.y = pack2(a4.z, a4.w);
        w2.z = pack2(a5.x, a5.y); w2.w = pack2(a5.z, a5.w);
        uint4* wp = (uint4*)(f16 + (row0 + r) * D_ + s * CPL);
        wp[0] = w0; wp[1] = w1; wp[2] = w2;

        float ss = a0.x*a0.x + a0.y*a0.y + a0.z*a0.z + a0.w*a0.w
                 + a1.x*a1.x + a1.y*a1.y + a1.z*a1.z + a1.w*a1.w
                 + a2.x*a2.x + a2.y*a2.y + a2.z*a2.z + a2.w*a2.w
                 + a3.x*a3.x + a3.y*a3.y + a3.z*a3.z + a3.w*a3.w
                 + a4.x*a4.x + a4.y*a4.y + a4.z*a4.z + a4.w*a4.w
                 + a5.x*a5.x + a5.y*a5.y + a5.z*a5.z + a5.w*a5.w;
        ss = half_sum(ss);
        if (s == 0) s_sal[r] = sqrtf(ss);
    }
    __syncthreads();

    const int rg = b * N_ + g * ROWS_PB;
    if (tid < ROWS_PB) {
        float n = s_sal[tid];
        sal[rg + tid]  = n;
        rsal[rg + tid] = 1.0f / fmaxf(n, 1e-12f);
        mask[rg + tid] = 1.0f;
    }
    if (wave == 0) {
        float v  = (lane < ROWS_PB) ? s_sal[lane] : -INFINITY;
        float sv = v;
        int   i  = (lane < ROWS_PB) ? (g * ROWS_PB + lane) : 0x7fffffff;
        #pragma unroll
        for (int off = 32; off; off >>= 1) {
            float ov = __shfl_xor(v, off);
            float osv = __shfl_xor(sv, off);
            int   oi = __shfl_xor(i, off);
            if (ov > v || (ov == v && oi < i)) { v = ov; sv = osv; i = oi; }
        }
        if (lane == 0) { argv[b*SLABS+g] = v; args[b*SLABS+g] = sv; argi[b*SLABS+g] = i; }
    }
}

// ---------------- Gram GEMM (upper-triangle, XCD-grouped, gload_lds, f32 G) ----------------
__global__ __launch_bounds__(THR)
void k_gram(const ushort* __restrict__ f16, float* __restrict__ G) {
    const int bid = blockIdx.x;
    const int xcd = bid & 7, slot = bid >> 3;
    const int batch = xcd + 8 * (slot / NTILE);
    int u = slot % NTILE;
    int trow = 0, cnt = 8;
    while (u >= cnt) { u -= cnt; --cnt; ++trow; }
    const int tcol = trow + u;
    const bool diag = (trow == tcol);

    const int tid = threadIdx.x, wave = tid >> 6, lane = tid & 63;
    const int wr = wave >> 1, wc = wave & 1;

    __shared__ __align__(16) ushort lA[128 * 64];
    __shared__ __align__(16) ushort lB[128 * 64];

    const ushort* Fb = f16 + (size_t)batch * N_ * D_;
    const int row0 = trow * 128, col0 = tcol * 128;

    f32x4 acc[4][4];
    #pragma unroll
    for (int i = 0; i < 4; ++i)
        #pragma unroll
        for (int j = 0; j < 4; ++j)
            acc[i][j] = (f32x4){0.f, 0.f, 0.f, 0.f};

    const ushort* lBr = diag ? lA : lB;

    for (int k0 = 0; k0 < D_; k0 += 64) {
        #pragma unroll
        for (int i = 0; i < 4; ++i) {
            const int d  = i * THR + tid;
            const int r  = d >> 3;
            const int kc = (d & 7) ^ (r & 7);
            gload_lds16(Fb + (size_t)(row0 + r) * D_ + k0 + kc * 8, lA + (size_t)d * 8);
            if (!diag)
                gload_lds16(Fb + (size_t)(col0 + r) * D_ + k0 + kc * 8, lB + (size_t)d * 8);
        }
        __syncthreads();

        #pragma unroll
        for (int ks = 0; ks < 2; ++ks) {
            half8 af[4], bf[4];
            #pragma unroll
            for (int fr = 0; fr < 4; ++fr) {
                const int rl = wr * 64 + fr * 16 + (lane & 15);
                const int kch = ks * 4 + (lane >> 4);
                af[fr] = *(const half8*)(lA + rl * 64 + ((kch ^ (rl & 7)) * 8));
            }
            #pragma unroll
            for (int fc = 0; fc < 4; ++fc) {
                const int cl = wc * 64 + fc * 16 + (lane & 15);
                const int kch = ks * 4 + (lane >> 4);
                bf[fc] = *(const half8*)(lBr + cl * 64 + ((kch ^ (cl & 7)) * 8));
            }
            #pragma unroll
            for (int fr = 0; fr < 4; ++fr)
                #pragma unroll
                for (int fc = 0; fc < 4; ++fc)
                    acc[fr][fc] = __builtin_amdgcn_mfma_f32_16x16x32_f16(
                        af[fr], bf[fc], acc[fr][fc], 0, 0, 0);
        }
        __syncthreads();
    }

    // epilogue: C/D mapping col=lane&15, row=(lane>>4)*4+q  [m89]
    float* Gb = G + ((size_t)batch << 20);
    #pragma unroll
    for (int fr = 0; fr < 4; ++fr) {
        #pragma unroll
        for (int fc = 0; fc < 4; ++fc) {
            const int rbase = row0 + wr * 64 + fr * 16 + (lane >> 4) * 4;
            const int c     = col0 + wc * 64 + fc * 16 + (lane & 15);
            #pragma unroll
            for (int q = 0; q < 4; ++q)
                Gb[(size_t)(rbase + q) * N_ + c] = acc[fr][fc][q];
        }
    }
}

// ---------------- slot loop: 1 wave per batch, register state, zero barriers ----------------
__global__ __launch_bounds__(64)
void k_slots(const float* __restrict__ G, const float* __restrict__ sal,
             const float* __restrict__ rsal, float* __restrict__ wbuf) {
    const int b = blockIdx.x, lane = threadIdx.x;
    const float* Gb = G + ((size_t)b << 20);

    float lsal[16], lrsal[16], lmask[16], lmsal[16];
    #pragma unroll
    for (int k = 0; k < 16; ++k) {
        const int n = lane + (k << 6);
        lsal[k]  = sal[b * N_ + n];
        lrsal[k] = rsal[b * N_ + n];
        lmask[k] = 1.0f;
        lmsal[k] = lsal[k];
    }

    for (int t = 0; t < T_; ++t) {
        // argmax (ties -> lowest index). Within-thread: n ascends with k, strict > keeps lowest.
        float v = lmsal[0]; int i = lane;
        #pragma unroll
        for (int k = 1; k < 16; ++k) {
            if (lmsal[k] > v) { v = lmsal[k]; i = lane + (k << 6); }
        }
        #pragma unroll
        for (int off = 32; off; off >>= 1) {
            float ov = __shfl_xor(v, off);
            int   oi = __shfl_xor(i, off);
            if (ov > v || (ov == v && oi < i)) { v = ov; i = oi; }
        }
        const int idx = i;
        const float rsi = rsal[b * N_ + idx];   // broadcast load

        #pragma unroll
        for (int k = 0; k < 16; ++k) {
            const int n = lane + (k << 6);
            float gv  = (n >= idx) ? Gb[(size_t)idx * N_ + n]
                                   : Gb[(size_t)n * N_ + idx];   // symmetric mirror
            float sim = gv * lrsal[k] * rsi;
            float m   = lmask[k];
            float w   = (sim > 0.5f) ? (sim * m) : 0.f;
            float nm  = m * (1.0f - fminf(fmaxf(sim, 0.f), 1.f));
            lmask[k] = nm;
            lmsal[k] = lsal[k] * nm;
            wbuf[((size_t)(b * T_ + t)) * N_ + n] = w;
        }
    }
}

// ---------------- W*F partials + per-rg wsum partials ----------------
__global__ __launch_bounds__(WFTHR)
void k_wf(const ushort* __restrict__ f16, const float* __restrict__ wbuf,
          float* __restrict__ part, float* __restrict__ wsp) {
    const int bid = blockIdx.x, b = bid >> 3, rg = bid & 7;
    const int tid = threadIdx.x;
    const int RPG = N_ / WFG;   // 128

    __shared__ float s_w[T_ * (N_ / WFG)];

    for (int idx = tid; idx < T_ * RPG; idx += WFTHR) {
        const int t = idx >> 7, r = idx & 127;
        s_w[idx] = wbuf[((size_t)(b * T_ + t)) * N_ + rg * RPG + r];
    }
    __syncthreads();

    // per-rg wsum partials
    if (tid < T_) {
        float s = 0.f;
        #pragma unroll 8
        for (int r = 0; r < RPG; ++r) s += s_w[tid * RPG + r];
        wsp[((size_t)(b * WFG + rg)) * T_ + tid] = s;
    }

    float acc[T_][4];
    #pragma unroll
    for (int t = 0; t < T_; ++t) {
        acc[t][0] = 0.f; acc[t][1] = 0.f; acc[t][2] = 0.f; acc[t][3] = 0.f;
    }

    const ushort* Fb = f16 + (size_t)b * N_ * D_;
    for (int r = 0; r < RPG; ++r) {
        const uint2 u = *(const uint2*)(Fb + (size_t)(rg * RPG + r) * D_ + tid * 4);
        __half2 h0 = *(__half2*)&u.x; float2 q0 = __half22float2(h0);
        __half2 h1 = *(__half2*)&u.y; float2 q1 = __half22float2(h1);
        const float f0 = q0.x, f1 = q0.y, f2 = q1.x, f3 = q1.y;
        const float* wr = s_w + r;
        #pragma unroll
        for (int t = 0; t < T_; ++t) {
            const float w = wr[t << 7];
            acc[t][0] = fmaf(w, f0, acc[t][0]);
            acc[t][1] = fmaf(w, f1, acc[t][1]);
            acc[t][2] = fmaf(w, f2, acc[t][2]);
            acc[t][3] = fmaf(w, f3, acc[t][3]);
        }
    }

    float* pb = part + (((size_t)(b * WFG + rg)) * T_) * D_;
    #pragma unroll
    for (int t = 0; t < T_; ++t) {
        float4 v; v.x = acc[t][0]; v.y = acc[t][1]; v.z = acc[t][2]; v.w = acc[t][3];
        *(float4*)(pb + (size_t)t * D_ + tid * 4) = v;
    }
}

// ---------------- final reduce + normalize ----------------
__global__ __launch_bounds__(THR)
void k_red(const float* __restrict__ part, const float* __restrict__ wsp,
           float* __restrict__ out) {
    const int bid = blockIdx.x, b = bid >> 4, t = bid & 15;
    const int tid = threadIdx.x;
    float den = 0.f;
    #pragma unroll
    for (int rg = 0; rg < WFG; ++rg)
        den += wsp[((size_t)(b * WFG + rg)) * T_ + t];
    den += 1e-8f;
    #pragma unroll
    for (int j = 0; j < 3; ++j) {
        const int c = tid + j * 256;
        float s = 0.f;
        #pragma unroll
        for (int rg = 0; rg < WFG; ++rg)
            s += part[(((size_t)(b * WFG + rg)) * T_ + t) * D_ + c];
        out[((size_t)(b * T_ + t)) * D_ + c] = s / den;
    }
}

// ================= fallback: r6 streaming path =================
__global__ __launch_bounds__(THR)
void k_fusedv(const ushort* __restrict__ f16, const float* __restrict__ sel,
              const float* __restrict__ sal, const float* __restrict__ rsal,
              float* __restrict__ mask, float* __restrict__ num,
              float* __restrict__ wsum, float* __restrict__ argv,
              float* __restrict__ args, int* __restrict__ argi) {
    const int blk = blockIdx.x, b = blk >> 5, g = blk & 31;
    const int tid = threadIdx.x, wave = tid >> 6, lane = tid & 63;
    const int h = lane >> 5, s = lane & 31;
    __shared__ __align__(16) float s_red[4 * D_];
    __shared__ float s_wsumW[4];
    __shared__ float s_msal[ROWS_PB];
    __shared__ float s_salL[ROWS_PB];
    const size_t row0 = (size_t)b * N_ + (size_t)g * ROWS_PB;
    const int rbase = b * N_ + g * ROWS_PB;
    const int r0 = wave * ROWS_PW;
    float se[CPL];
    {
        const float4* sp = (const float4*)(sel + (size_t)b * D_ + s * CPL);
        #pragma unroll
        for (int q = 0; q < 6; ++q) {
            float4 v = sp[q];
            se[q*4+0] = v.x; se[q*4+1] = v.y; se[q*4+2] = v.z; se[q*4+3] = v.w;
        }
    }
    float acc[CPL];
    #pragma unroll
    for (int i = 0; i < CPL; ++i) acc[i] = 0.f;
    float wsl = 0.f;
    #pragma unroll
    for (int rp = 0; rp < ROWS_PW / 2; ++rp) {
        const int r = r0 + rp * 2 + h;
        const uint4* dp = (const uint4*)(f16 + (row0 + r) * D_ + s * CPL);
        uint4 u0 = dp[0], u1 = dp[1], u2 = dp[2];
        float f[CPL];
        unpack8(u0, f); unpack8(u1, f + 8); unpack8(u2, f + 16);
        float dot = 0.f;
        #pragma unroll
        for (int i = 0; i < CPL; ++i) dot = fmaf(f[i], se[i], dot);
        dot = half_sum(dot);
        float rs  = rsal[rbase + r];
        float sv  = sal[rbase + r];
        float m   = mask[rbase + r];
        float sim = dot * rs;
        float wr  = (sim > 0.5f) ? (sim * m) : 0.f;
        float nm  = m * (1.0f - fminf(fmaxf(sim, 0.f), 1.f));
        if (s == 0) { mask[rbase + r] = nm; s_msal[r] = sv * nm; s_salL[r] = sv; }
        wsl += wr;
        #pragma unroll
        for (int i = 0; i < CPL; ++i) acc[i] = fmaf(wr, f[i], acc[i]);
    }
    wsl += __shfl_xor(wsl, 32);
    #pragma unroll
    for (int i = 0; i < CPL; ++i) acc[i] += __shfl_xor(acc[i], 32);
    if (h == 0) {
        float4* rw = (float4*)(s_red + wave * D_ + s * CPL);
        #pragma unroll
        for (int q = 0; q < 6; ++q) {
            float4 v;
            v.x = acc[q*4+0]; v.y = acc[q*4+1]; v.z = acc[q*4+2]; v.w = acc[q*4+3];
            rw[q] = v;
        }
    }
    if (lane == 0) s_wsumW[wave] = wsl;
    __syncthreads();
    #pragma unroll
    for (int it = 0; it < 3; ++it) {
        const int c = it * THR + tid;
        float sm = s_red[c] + s_red[D_ + c] + s_red[2*D_ + c] + s_red[3*D_ + c];
        num[((size_t)b * SLABS + g) * D_ + c] = sm;
    }
    if (tid == 0)
        wsum[b*SLABS+g] = s_wsumW[0] + s_wsumW[1] + s_wsumW[2] + s_wsumW[3];
    if (wave == 0) {
        float v  = (lane < ROWS_PB) ? s_msal[lane] : -INFINITY;
        float sv = (lane < ROWS_PB) ? s_salL[lane] : 0.f;
        int   i  = (lane < ROWS_PB) ? (g * ROWS_PB + lane) : 0x7fffffff;
        #pragma unroll
        for (int off = 32; off; off >>= 1) {
            float ov = __shfl_xor(v, off);
            float osv = __shfl_xor(sv, off);
            int   oi = __shfl_xor(i, off);
            if (ov > v || (ov == v && oi < i)) { v = ov; sv = osv; i = oi; }
        }
        if (lane == 0) { argv[b*SLABS+g] = v; args[b*SLABS+g] = sv; argi[b*SLABS+g] = i; }
    }
}

__global__ __launch_bounds__(192)
void k_out(const float* __restrict__ feat, const float* __restrict__ num,
           const float* __restrict__ wsumA, const float* __restrict__ argv,
           const float* __restrict__ args, const int* __restrict__ argi,
           float* __restrict__ sel, float* __restrict__ out, int t) {
    const int b = blockIdx.x >> 2, q = blockIdx.x & 3;
    const int tid = threadIdx.x, lane = tid & 63;
    __shared__ float s_rsel;
    __shared__ int   s_idx;
    __shared__ float s_ws;
    if (tid < 64) {
        float v  = (lane < SLABS) ? argv[b*SLABS + lane] : -INFINITY;
        float sv = (lane < SLABS) ? args[b*SLABS + lane] : 0.f;
        int   i  = (lane < SLABS) ? argi[b*SLABS + lane] : 0x7fffffff;
        float w  = (lane < SLABS) ? wsumA[b*SLABS + lane] : 0.f;
        #pragma unroll
        for (int off = 32; off; off >>= 1) {
            float ov = __shfl_xor(v, off);
            float osv = __shfl_xor(sv, off);
            int   oi = __shfl_xor(i, off);
            w += __shfl_xor(w, off);
            if (ov > v || (ov == v && oi < i)) { v = ov; sv = osv; i = oi; }
        }
        if (lane == 0) { s_idx = i; s_rsel = 1.0f / fmaxf(sv, 1e-12f); s_ws = w; }
    }
    __syncthreads();
    const int c = q * 192 + tid;
    if (t >= 0) {
        float sm = 0.f;
        #pragma unroll 8
        for (int g = 0; g < SLABS; ++g)
            sm += num[((size_t)b * SLABS + g) * D_ + c];
        out[((size_t)b * T_ + t) * D_ + c] = sm / (s_ws + 1e-8f);
    }
    sel[(size_t)b * D_ + c] = feat[((size_t)b * N_ + s_idx) * D_ + c] * s_rsel;
}

extern "C" void kernel_launch(void* const* d_in, const int* in_sizes, int n_in,
                              void* d_out, int out_size, void* d_ws, size_t ws_size,
                              hipStream_t stream) {
    const float* feat = (const float*)d_in[0];
    float* out = (float*)d_out;
    (void)in_sizes; (void)n_in; (void)out_size;

    const size_t n_sal  = (size_t)B_ * N_;
    const size_t n_arg  = (size_t)B_ * SLABS;
    const size_t n_sel  = (size_t)B_ * D_;
    const size_t n_num  = (size_t)B_ * SLABS * D_;
    const size_t n_f16  = (size_t)B_ * N_ * D_;
    const size_t n_G    = (size_t)B_ * N_ * N_;      // f32
    const size_t n_wbuf = (size_t)B_ * T_ * N_;
    const size_t n_part = (size_t)B_ * WFG * T_ * D_;
    const size_t n_wsp  = (size_t)B_ * WFG * T_;

    const size_t f16_bytes = (n_f16 * sizeof(ushort) + 255) & ~(size_t)255;

    const size_t need_gram = f16_bytes
        + (n_G + n_wbuf + n_part + n_wsp + 3*n_sal + 3*n_arg) * sizeof(float) + 4096;
    const size_t need_mk = f16_bytes
        + (3*n_sal + 4*n_arg + n_sel + n_num) * sizeof(float) + 1024;

    if (ws_size >= need_gram) {
        char* base = (char*)d_ws;
        ushort* f16 = (ushort*)base;
        float* p = (float*)(base + f16_bytes);
        float* G     = p;        p += n_G;
        float* wbuf  = p;        p += n_wbuf;
        float* part  = p;        p += n_part;
        float* wsp   = p;        p += n_wsp;
        float* sal   = p;        p += n_sal;
        float* rsal  = p;        p += n_sal;
        float* mask  = p;        p += n_sal;
        float* argvD = p;        p += n_arg;
        float* argsD = p;        p += n_arg;
        int*   argiD = (int*)p;  p += n_arg;

        k_sal16v<<<B_*SLABS, THR, 0, stream>>>(feat, f16, sal, rsal, mask,
                                               argvD, argsD, argiD);
        k_gram<<<B_*NTILE, THR, 0, stream>>>(f16, G);
        k_slots<<<B_, 64, 0, stream>>>(G, sal, rsal, wbuf);
        k_wf<<<B_*WFG, WFTHR, 0, stream>>>(f16, wbuf, part, wsp);
        k_red<<<B_*T_, THR, 0, stream>>>(part, wsp, out);
        return;
    }

    if (ws_size >= need_mk) {
        char* base = (char*)d_ws;
        ushort* f16 = (ushort*)base;
        float* p = (float*)(base + f16_bytes);
        float* sal  = p;            p += n_sal;
        float* rsal = p;            p += n_sal;
        float* mask = p;            p += n_sal;
        float* argv = p;            p += n_arg;
        float* args = p;            p += n_arg;
        int*   argi = (int*)p;      p += n_arg;
        float* wsum = p;            p += n_arg;
        float* sel  = p;            p += n_sel;
        float* num  = p;            p += n_num;

        k_sal16v<<<B_*SLABS, THR, 0, stream>>>(feat, f16, sal, rsal, mask, argv, args, argi);
        k_out<<<B_*4, 192, 0, stream>>>(feat, num, wsum, argv, args, argi, sel, out, -1);
        for (int t = 0; t < T_; ++t) {
            k_fusedv<<<B_*SLABS, THR, 0, stream>>>(f16, sel, sal, rsal, mask,
                                                   num, wsum, argv, args, argi);
            k_out<<<B_*4, 192, 0, stream>>>(feat, num, wsum, argv, args, argi, sel, out, t);
        }
        return;
    }
}